// Round 3
// baseline (602.337 us; speedup 1.0000x reference)
//
#include <hip/hip_runtime.h>
#include <math.h>

#define C 384
#define NF 16
#define H 256
#define Bb 4
#define Kk 2048
#define Nn 16384
#define MW 16           // nodes per wave
#define WPB 4           // waves per block
#define LDA 392         // act row stride in shorts (rows offset 4 banks -> free 2-way)

typedef __attribute__((ext_vector_type(8))) short bf16x8;
typedef __attribute__((ext_vector_type(4))) float f32x4;
typedef __attribute__((ext_vector_type(4))) short s16x4;

// ws layout (shorts)
#define POS_OFF 0            // pos_w  [384][32]
#define Q1_OFF  12288        // q_w1   [384][384]
#define Q2_OFF  159744       // q_w2   [384][384]
#define M1_OFF  307200       // m_w1   [256][384]
#define M2_OFF  405504       // m_w2   [256][256]
#define M3_OFF  471040       // m_w3 padded [16][256], rows>=3 zero
#define W_TOTAL 475136

__device__ inline short f2bf(float x) {
    union { float f; unsigned u; } v; v.f = x;
    unsigned r = (v.u + 0x7FFFu + ((v.u >> 16) & 1u)) >> 16;
    return (short)r;
}

// ---------------- weight f32->bf16 conversion into workspace ----------------
__global__ __launch_bounds__(256) void conv_w(
    const float* __restrict__ pos_w, const float* __restrict__ q_w1,
    const float* __restrict__ q_w2,  const float* __restrict__ m_w1,
    const float* __restrict__ m_w2,  const float* __restrict__ m_w3,
    short* __restrict__ ws)
{
    int i = blockIdx.x * 256 + threadIdx.x;
    if (i >= W_TOTAL) return;
    float v;
    if      (i < Q1_OFF) v = pos_w[i - POS_OFF];
    else if (i < Q2_OFF) v = q_w1[i - Q1_OFF];
    else if (i < M1_OFF) v = q_w2[i - Q2_OFF];
    else if (i < M2_OFF) v = m_w1[i - M1_OFF];
    else if (i < M3_OFF) v = m_w2[i - M2_OFF];
    else {
        int t = i - M3_OFF;
        int r = t >> 8, k = t & 255;
        v = (r < 3) ? m_w3[r * 256 + k] : 0.f;
    }
    ws[i] = f2bf(v);
}

// ---- one MFMA FC layer for this wave's 16 nodes; acc register-resident ----
// out[m][f] = act( in[m][:K] @ W[f][:K] + bias[f] ) [*mask] [+gather] [-> LN]
template<int K, int NT, bool GATHER, bool SILU, bool MASK, bool LNF>
__device__ __attribute__((always_inline)) inline void layer_mfma(
    const short* __restrict__ W, const float* __restrict__ bias,
    const float* __restrict__ lng, const float* __restrict__ lnb,
    const float* __restrict__ gbase,
    short (*__restrict__ actw)[LDA],
    const int* __restrict__ idxw, const float* __restrict__ maskw,
    int q, int ln)
{
    f32x4 acc[NT];
    #pragma unroll
    for (int nt = 0; nt < NT; ++nt) acc[nt] = (f32x4){0.f, 0.f, 0.f, 0.f};

    #pragma unroll 2
    for (int kk = 0; kk < K; kk += 32) {
        const int ko = kk + q * 8;
        bf16x8 a = *(const bf16x8*)&actw[ln][ko];
        #pragma unroll
        for (int nt = 0; nt < NT; ++nt) {
            bf16x8 bf = *(const bf16x8*)&W[(nt * 16 + ln) * K + ko];
            acc[nt] = __builtin_amdgcn_mfma_f32_16x16x32_bf16(a, bf, acc[nt], 0, 0, 0);
        }
    }

    float mk[4]; int ix[4];
    #pragma unroll
    for (int r = 0; r < 4; ++r) {
        mk[r] = maskw[q * 4 + r];
        if (GATHER) ix[r] = idxw[q * 4 + r];
    }

    float s1[4] = {0.f,0.f,0.f,0.f}, s2[4] = {0.f,0.f,0.f,0.f};
    #pragma unroll
    for (int nt = 0; nt < NT; ++nt) {
        const int f = nt * 16 + ln;
        float bv = bias[f];
        #pragma unroll
        for (int r = 0; r < 4; ++r) {
            float v = acc[nt][r] + bv;
            if (SILU) v = v / (1.f + __expf(-v));
            if (MASK) v *= mk[r];
            if (GATHER) v += gbase[(long)ix[r] * C + f];
            if (LNF) { s1[r] += v; s2[r] += v * v; acc[nt][r] = v; }
            else       actw[q * 4 + r][f] = f2bf(v);
        }
    }

    if (LNF) {
        // node rows live within one quad: reduce across the 16 lanes of the quad
        #pragma unroll
        for (int d = 1; d < 16; d <<= 1) {
            #pragma unroll
            for (int r = 0; r < 4; ++r) {
                s1[r] += __shfl_xor(s1[r], d);
                s2[r] += __shfl_xor(s2[r], d);
            }
        }
        constexpr float invF = 1.f / (NT * 16);
        float mean[4], rstd[4];
        #pragma unroll
        for (int r = 0; r < 4; ++r) {
            mean[r] = s1[r] * invF;
            float var = s2[r] * invF - mean[r] * mean[r];
            rstd[r] = rsqrtf(var + 1e-5f);
        }
        #pragma unroll
        for (int nt = 0; nt < NT; ++nt) {
            const int f = nt * 16 + ln;
            float g = lng[f], bb = lnb[f];
            #pragma unroll
            for (int r = 0; r < 4; ++r) {
                float v = (acc[nt][r] - mean[r]) * rstd[r] * g + bb;
                actw[q * 4 + r][f] = f2bf(v);
            }
        }
    }
}

__global__ __launch_bounds__(256, 3) void upxi_wave(
    const float* __restrict__ s_parent, const float* __restrict__ mu_k,
    const float* __restrict__ R_k,      const float* __restrict__ s_k,
    const int*   __restrict__ a_idx,    const float* __restrict__ node_mask,
    const float* __restrict__ pos01,
    const float* __restrict__ pos_b,
    const float* __restrict__ q_ln_g,   const float* __restrict__ q_ln_b,
    const float* __restrict__ q_b1,     const float* __restrict__ q_b2,
    const float* __restrict__ m_ln_g,   const float* __restrict__ m_ln_b,
    const float* __restrict__ m_b1,     const float* __restrict__ m_b2,
    const float* __restrict__ m_b3,
    const short* __restrict__ wsb,
    float* __restrict__ out)
{
    __shared__ short act[WPB][MW][LDA];
    __shared__ int   widx[WPB][MW];
    __shared__ float wmask[WPB][MW];
    __shared__ float wpos[WPB][MW];
    __shared__ float xis[WPB][MW][4];

    const int tid  = threadIdx.x;
    const int w    = tid >> 6;
    const int lane = tid & 63;
    const int q    = lane >> 4;
    const int ln   = lane & 15;

    const int gwv = blockIdx.x * WPB + w;
    const int g0  = gwv * MW;
    const int b   = g0 / Nn;
    const int n0  = g0 % Nn;

    short (*__restrict__ actw)[LDA] = act[w];
    const int*   idxw  = widx[w];
    const float* maskw = wmask[w];

    // -------- per-node scalars (wave-local, no barriers anywhere) --------
    if (lane < MW) {
        int gi = b * Nn + n0 + lane;
        int idx = a_idx[gi];
        widx[w][lane]  = min(max(idx, 0), Kk - 1);
        wmask[w][lane] = node_mask[gi];
        wpos[w][lane]  = pos01[gi];
    }

    // -------- fourier feats -> act[m][0..31] (sin | cos), bf16 --------
    {
        int m  = lane >> 2;
        int j0 = (lane & 3) * 4;
        float p = wpos[w][m];
        s16x4 sv4, cv4;
        #pragma unroll
        for (int jj = 0; jj < 4; ++jj) {
            float freq = (float)(1 << (j0 + jj)) * 3.14159265358979323846f;
            float sg, cg;
            __sincosf(p * freq, &sg, &cg);
            sv4[jj] = f2bf(sg);
            cv4[jj] = f2bf(cg);
        }
        *(s16x4*)&actw[m][j0]      = sv4;
        *(s16x4*)&actw[m][16 + j0] = cv4;
    }

    const float* gbase = s_parent + (long)b * Kk * C;

    // pos_emb (K=32) +bias *mask +gather(s_parent) -> q_LN -> act
    layer_mfma<32, 24, true, false, true, true>(
        wsb + POS_OFF, pos_b, q_ln_g, q_ln_b, gbase, actw, idxw, maskw, q, ln);
    // q1: silu(x@q_w1^T + b1)
    layer_mfma<C, 24, false, true, false, false>(
        wsb + Q1_OFF, q_b1, nullptr, nullptr, nullptr, actw, idxw, maskw, q, ln);
    // q2: (x@q_w2^T + b2)*mask -> m_LN
    layer_mfma<C, 24, false, false, true, true>(
        wsb + Q2_OFF, q_b2, m_ln_g, m_ln_b, nullptr, actw, idxw, maskw, q, ln);
    // m1: silu(x@m_w1^T + b1)  (384 -> 256)
    layer_mfma<C, 16, false, true, false, false>(
        wsb + M1_OFF, m_b1, nullptr, nullptr, nullptr, actw, idxw, maskw, q, ln);
    // m2: silu(x@m_w2^T + b2)  (256 -> 256)
    layer_mfma<H, 16, false, true, false, false>(
        wsb + M2_OFF, m_b2, nullptr, nullptr, nullptr, actw, idxw, maskw, q, ln);

    // -------- final 256->3 via padded-16 MFMA, tanh*1.5 --------
    {
        const short* W3 = wsb + M3_OFF;
        f32x4 a3 = (f32x4){0.f, 0.f, 0.f, 0.f};
        #pragma unroll
        for (int kk = 0; kk < H; kk += 32) {
            const int ko = kk + q * 8;
            bf16x8 a  = *(const bf16x8*)&actw[ln][ko];
            bf16x8 bf = *(const bf16x8*)&W3[ln * H + ko];
            a3 = __builtin_amdgcn_mfma_f32_16x16x32_bf16(a, bf, a3, 0, 0, 0);
        }
        if (ln < 3) {
            float bv = m_b3[ln];
            #pragma unroll
            for (int r = 0; r < 4; ++r) {
                int m = q * 4 + r;
                float v = (a3[r] + bv) * wmask[w][m];
                xis[w][m][ln] = tanhf(v) * 1.5f;
            }
        }
    }

    // -------- rigid apply + outputs (lanes 0..15, same wave) --------
    if (lane < MW) {
        int m = lane;
        long gi = (long)b * Nn + n0 + m;
        long pk = (long)b * Kk + widx[w][m];
        float mkv = wmask[w][m];
        float xv[3], yv[3], xiv[3];
        #pragma unroll
        for (int j = 0; j < 3; ++j) {
            xiv[j] = xis[w][m][j];
            float sc = fmaxf(s_k[pk * 3 + j], 1e-8f);
            xv[j] = xiv[j] * sc;
        }
        #pragma unroll
        for (int i = 0; i < 3; ++i) {
            float a = R_k[pk * 9 + i * 3 + 0] * xv[0]
                    + R_k[pk * 9 + i * 3 + 1] * xv[1]
                    + R_k[pk * 9 + i * 3 + 2] * xv[2]
                    + mu_k[pk * 3 + i];
            yv[i] = a * mkv * 10.f;
        }
        float* o0 = out;
        float* o1 = out + (long)Bb * Nn * 3;
        float* o2 = out + (long)Bb * Nn * 6;
        #pragma unroll
        for (int j = 0; j < 3; ++j) { o0[gi * 3 + j] = xiv[j]; o1[gi * 3 + j] = yv[j]; }
        o2[gi] = wpos[w][m];
    }
}

extern "C" void kernel_launch(void* const* d_in, const int* in_sizes, int n_in,
                              void* d_out, int out_size, void* d_ws, size_t ws_size,
                              hipStream_t stream) {
    const float* s_parent = (const float*)d_in[0];
    const float* mu_k     = (const float*)d_in[1];
    const float* R_k      = (const float*)d_in[2];
    const float* s_k      = (const float*)d_in[3];
    const int*   a_idx    = (const int*)  d_in[4];
    const float* node_mask= (const float*)d_in[5];
    const float* pos01    = (const float*)d_in[6];
    const float* pos_w    = (const float*)d_in[7];
    const float* pos_b    = (const float*)d_in[8];
    const float* q_ln_g   = (const float*)d_in[9];
    const float* q_ln_b   = (const float*)d_in[10];
    const float* q_w1     = (const float*)d_in[11];
    const float* q_b1     = (const float*)d_in[12];
    const float* q_w2     = (const float*)d_in[13];
    const float* q_b2     = (const float*)d_in[14];
    const float* m_ln_g   = (const float*)d_in[15];
    const float* m_ln_b   = (const float*)d_in[16];
    const float* m_w1     = (const float*)d_in[17];
    const float* m_b1     = (const float*)d_in[18];
    const float* m_w2     = (const float*)d_in[19];
    const float* m_b2     = (const float*)d_in[20];
    const float* m_w3     = (const float*)d_in[21];
    const float* m_b3     = (const float*)d_in[22];

    short* wsb = (short*)d_ws;

    conv_w<<<(W_TOTAL + 255) / 256, 256, 0, stream>>>(
        pos_w, q_w1, q_w2, m_w1, m_w2, m_w3, wsb);

    int blocks = (Bb * Nn) / (WPB * MW);  // 1024
    upxi_wave<<<blocks, 256, 0, stream>>>(
        s_parent, mu_k, R_k, s_k, a_idx, node_mask, pos01,
        pos_b, q_ln_g, q_ln_b, q_b1, q_b2,
        m_ln_g, m_ln_b, m_b1, m_b2, m_b3,
        wsb, (float*)d_out);
}

// Round 4
// 316.906 us; speedup vs baseline: 1.9007x; 1.9007x over previous
//
#include <hip/hip_runtime.h>
#include <math.h>

#define C 384
#define NF 16
#define H 256
#define Bb 4
#define Kk 2048
#define Nn 16384
#define MB 64           // nodes per block (4 m-tiles)
#define LDA 392         // act row stride in shorts

typedef __attribute__((ext_vector_type(8))) short bf16x8;
typedef __attribute__((ext_vector_type(4))) float f32x4;

// ws layout (shorts)
#define POS_OFF 0            // pos_w  [384][32]
#define Q1_OFF  12288        // q_w1   [384][384]
#define Q2_OFF  159744       // q_w2   [384][384]
#define M1_OFF  307200       // m_w1   [256][384]
#define M2_OFF  405504       // m_w2   [256][256]
#define M3_OFF  471040       // m_w3 padded [16][256], rows>=3 zero
#define W_TOTAL 475136

__device__ inline short f2bf(float x) {
    union { float f; unsigned u; } v; v.f = x;
    unsigned r = (v.u + 0x7FFFu + ((v.u >> 16) & 1u)) >> 16;
    return (short)r;
}
__device__ inline float bf2f(short s) {
    union { unsigned u; float f; } v; v.u = ((unsigned)(unsigned short)s) << 16;
    return v.f;
}

__global__ __launch_bounds__(256) void conv_w(
    const float* __restrict__ pos_w, const float* __restrict__ q_w1,
    const float* __restrict__ q_w2,  const float* __restrict__ m_w1,
    const float* __restrict__ m_w2,  const float* __restrict__ m_w3,
    short* __restrict__ ws)
{
    int i = blockIdx.x * 256 + threadIdx.x;
    if (i >= W_TOTAL) return;
    float v;
    if      (i < Q1_OFF) v = pos_w[i - POS_OFF];
    else if (i < Q2_OFF) v = q_w1[i - Q1_OFF];
    else if (i < M1_OFF) v = q_w2[i - Q2_OFF];
    else if (i < M2_OFF) v = m_w1[i - M1_OFF];
    else if (i < M3_OFF) v = m_w2[i - M2_OFF];
    else {
        int t = i - M3_OFF;
        int r = t >> 8, k = t & 255;
        v = (r < 3) ? m_w3[r * 256 + k] : 0.f;
    }
    ws[i] = f2bf(v);
}

// LN apply over 384-wide rows; stats already in sc1/sc2 (per-wave partials).
__device__ __attribute__((always_inline)) inline void ln_apply(
    short (*__restrict__ xs)[LDA], const float* __restrict__ g,
    const float* __restrict__ bb,
    float (*__restrict__ sc1)[4], float (*__restrict__ sc2)[4], int tid)
{
    int m = tid >> 2, j = tid & 3;
    float s1 = sc1[m][0] + sc1[m][1] + sc1[m][2] + sc1[m][3];
    float s2 = sc2[m][0] + sc2[m][1] + sc2[m][2] + sc2[m][3];
    float mean = s1 * (1.f / 384.f);
    float var  = s2 * (1.f / 384.f) - mean * mean;
    float rstd = rsqrtf(var + 1e-5f);
    int c0 = j * 96;
    #pragma unroll
    for (int i = 0; i < 12; ++i) {
        int cc = c0 + i * 8;
        bf16x8 v8 = *(bf16x8*)&xs[m][cc];
        bf16x8 o8;
        #pragma unroll
        for (int e = 0; e < 8; ++e) {
            float v = (bf2f(v8[e]) - mean) * rstd * g[cc + e] + bb[cc + e];
            o8[e] = f2bf(v);
        }
        *(bf16x8*)&xs[m][cc] = o8;
    }
}

// In-place FC layer: reads xs[:,0:K] (all waves), barrier, writes its feature
// slice xs[:, FB:FB+NT*16]. 4 m-tiles per wave. Two barriers inside.
template<int K, int NT, bool SILU, bool MASK, bool STATS>
__device__ __attribute__((always_inline)) inline void layer_ip(
    const short* __restrict__ W, const float* __restrict__ bias, int FB,
    short (*__restrict__ xs)[LDA],
    float (*__restrict__ sc1)[4], float (*__restrict__ sc2)[4],
    const float* __restrict__ wmask, int w, int q, int ln)
{
    const short* Ws = W + (size_t)FB * K;
    f32x4 acc[4][NT];
    #pragma unroll
    for (int mt = 0; mt < 4; ++mt)
        #pragma unroll
        for (int nt = 0; nt < NT; ++nt)
            acc[mt][nt] = (f32x4){0.f, 0.f, 0.f, 0.f};

    for (int kk = 0; kk < K; kk += 32) {
        const int ko = kk + q * 8;
        bf16x8 a[4];
        #pragma unroll
        for (int mt = 0; mt < 4; ++mt)
            a[mt] = *(const bf16x8*)&xs[mt * 16 + ln][ko];
        #pragma unroll
        for (int nt = 0; nt < NT; ++nt) {
            bf16x8 bfr = *(const bf16x8*)&Ws[(size_t)(nt * 16 + ln) * K + ko];
            #pragma unroll
            for (int mt = 0; mt < 4; ++mt)
                acc[mt][nt] = __builtin_amdgcn_mfma_f32_16x16x32_bf16(a[mt], bfr, acc[mt][nt], 0, 0, 0);
        }
    }
    __syncthreads();   // all reads of xs complete before any in-place write

    float s1[4][4], s2[4][4];
    if (STATS) {
        #pragma unroll
        for (int mt = 0; mt < 4; ++mt)
            #pragma unroll
            for (int r = 0; r < 4; ++r) { s1[mt][r] = 0.f; s2[mt][r] = 0.f; }
    }
    #pragma unroll
    for (int nt = 0; nt < NT; ++nt) {
        const int f = FB + nt * 16 + ln;
        float bv = bias[f];
        #pragma unroll
        for (int mt = 0; mt < 4; ++mt) {
            #pragma unroll
            for (int r = 0; r < 4; ++r) {
                int m = mt * 16 + q * 4 + r;
                float v = acc[mt][nt][r] + bv;
                if (SILU) v = v / (1.f + __expf(-v));
                if (MASK) v *= wmask[m];
                if (STATS) { s1[mt][r] += v; s2[mt][r] += v * v; }
                xs[m][f] = f2bf(v);
            }
        }
    }
    if (STATS) {
        #pragma unroll
        for (int d = 1; d < 16; d <<= 1) {
            #pragma unroll
            for (int mt = 0; mt < 4; ++mt)
                #pragma unroll
                for (int r = 0; r < 4; ++r) {
                    s1[mt][r] += __shfl_xor(s1[mt][r], d);
                    s2[mt][r] += __shfl_xor(s2[mt][r], d);
                }
        }
        if (ln == 0) {
            #pragma unroll
            for (int mt = 0; mt < 4; ++mt)
                #pragma unroll
                for (int r = 0; r < 4; ++r) {
                    int m = mt * 16 + q * 4 + r;
                    sc1[m][w] = s1[mt][r];
                    sc2[m][w] = s2[mt][r];
                }
        }
    }
    __syncthreads();   // writes visible before next layer reads
}

__global__ __launch_bounds__(256, 3) void upxi64(
    const float* __restrict__ s_parent, const float* __restrict__ mu_k,
    const float* __restrict__ R_k,      const float* __restrict__ s_k,
    const int*   __restrict__ a_idx,    const float* __restrict__ node_mask,
    const float* __restrict__ pos01,
    const float* __restrict__ pos_b,
    const float* __restrict__ q_ln_g,   const float* __restrict__ q_ln_b,
    const float* __restrict__ q_b1,     const float* __restrict__ q_b2,
    const float* __restrict__ m_ln_g,   const float* __restrict__ m_ln_b,
    const float* __restrict__ m_b1,     const float* __restrict__ m_b2,
    const float* __restrict__ m_b3,
    const short* __restrict__ wsb,
    float* __restrict__ out)
{
    __shared__ short xs[MB][LDA];       // 50176 B
    __shared__ float sc1[MB][4];        // 1024 B (reused as xi store in tail)
    __shared__ float sc2[MB][4];        // 1024 B
    __shared__ float wmask[MB], wpos[MB];
    __shared__ int   widx[MB];

    const int tid  = threadIdx.x;
    const int w    = tid >> 6;
    const int lane = tid & 63;
    const int q    = lane >> 4;
    const int ln   = lane & 15;

    const int g0 = blockIdx.x * MB;
    const int b  = g0 / Nn;
    const int n0 = g0 % Nn;

    if (tid < MB) {
        int gi = b * Nn + n0 + tid;
        int idx = a_idx[gi];
        widx[tid]  = min(max(idx, 0), Kk - 1);
        wmask[tid] = node_mask[gi];
        wpos[tid]  = pos01[gi];
    }
    __syncthreads();

    const float* gbase = s_parent + (long)b * Kk * C;

    // ---- pos layer: A built in registers (sincos), +pos_b, *mask, +gather, stats for q-LN ----
    {
        const short* pos_wb = wsb + POS_OFF;
        const bool use_sin = (q < 2);
        const int kb = (q & 1) * 8;
        bf16x8 a[4];
        #pragma unroll
        for (int mt = 0; mt < 4; ++mt) {
            float p = wpos[mt * 16 + ln];
            #pragma unroll
            for (int e = 0; e < 8; ++e) {
                float fr = (float)(1 << (kb + e)) * 3.14159265358979323846f;
                float sv, cv;
                __sincosf(p * fr, &sv, &cv);
                a[mt][e] = f2bf(use_sin ? sv : cv);
            }
        }
        f32x4 acc[4][6];
        #pragma unroll
        for (int mt = 0; mt < 4; ++mt)
            #pragma unroll
            for (int nt = 0; nt < 6; ++nt)
                acc[mt][nt] = (f32x4){0.f, 0.f, 0.f, 0.f};
        #pragma unroll
        for (int nt = 0; nt < 6; ++nt) {
            int f = w * 96 + nt * 16 + ln;
            bf16x8 bfr = *(const bf16x8*)&pos_wb[f * 32 + q * 8];
            #pragma unroll
            for (int mt = 0; mt < 4; ++mt)
                acc[mt][nt] = __builtin_amdgcn_mfma_f32_16x16x32_bf16(a[mt], bfr, acc[mt][nt], 0, 0, 0);
        }
        float s1[4][4], s2[4][4];
        #pragma unroll
        for (int mt = 0; mt < 4; ++mt)
            #pragma unroll
            for (int r = 0; r < 4; ++r) { s1[mt][r] = 0.f; s2[mt][r] = 0.f; }
        #pragma unroll
        for (int nt = 0; nt < 6; ++nt) {
            int f = w * 96 + nt * 16 + ln;
            float pbv = pos_b[f];
            #pragma unroll
            for (int mt = 0; mt < 4; ++mt) {
                #pragma unroll
                for (int r = 0; r < 4; ++r) {
                    int m = mt * 16 + q * 4 + r;
                    float v = (acc[mt][nt][r] + pbv) * wmask[m]
                            + gbase[(long)widx[m] * C + f];
                    s1[mt][r] += v; s2[mt][r] += v * v;
                    xs[m][f] = f2bf(v);
                }
            }
        }
        #pragma unroll
        for (int d = 1; d < 16; d <<= 1) {
            #pragma unroll
            for (int mt = 0; mt < 4; ++mt)
                #pragma unroll
                for (int r = 0; r < 4; ++r) {
                    s1[mt][r] += __shfl_xor(s1[mt][r], d);
                    s2[mt][r] += __shfl_xor(s2[mt][r], d);
                }
        }
        if (ln == 0) {
            #pragma unroll
            for (int mt = 0; mt < 4; ++mt)
                #pragma unroll
                for (int r = 0; r < 4; ++r) {
                    int m = mt * 16 + q * 4 + r;
                    sc1[m][w] = s1[mt][r];
                    sc2[m][w] = s2[mt][r];
                }
        }
    }
    __syncthreads();

    ln_apply(xs, q_ln_g, q_ln_b, sc1, sc2, tid);
    __syncthreads();

    layer_ip<384, 6, true,  false, false>(wsb + Q1_OFF, q_b1, w * 96, xs, sc1, sc2, wmask, w, q, ln);
    layer_ip<384, 6, false, true,  true >(wsb + Q2_OFF, q_b2, w * 96, xs, sc1, sc2, wmask, w, q, ln);

    ln_apply(xs, m_ln_g, m_ln_b, sc1, sc2, tid);
    __syncthreads();

    layer_ip<384, 4, true, false, false>(wsb + M1_OFF, m_b1, w * 64, xs, sc1, sc2, wmask, w, q, ln);
    layer_ip<256, 4, true, false, false>(wsb + M2_OFF, m_b2, w * 64, xs, sc1, sc2, wmask, w, q, ln);

    // ---- tail: 256->3 MFMA (wave w owns m-tile w), tanh*1.5 ----
    {
        const short* W3 = wsb + M3_OFF;
        f32x4 a3 = (f32x4){0.f, 0.f, 0.f, 0.f};
        #pragma unroll
        for (int kk = 0; kk < H; kk += 32) {
            const int ko = kk + q * 8;
            bf16x8 a  = *(const bf16x8*)&xs[w * 16 + ln][ko];
            bf16x8 bf = *(const bf16x8*)&W3[ln * H + ko];
            a3 = __builtin_amdgcn_mfma_f32_16x16x32_bf16(a, bf, a3, 0, 0, 0);
        }
        if (ln < 3) {
            float bv = m_b3[ln];
            #pragma unroll
            for (int r = 0; r < 4; ++r) {
                int m = w * 16 + q * 4 + r;
                float v = (a3[r] + bv) * wmask[m];
                sc1[m][ln] = tanhf(v) * 1.5f;
            }
        }
    }

    // ---- rigid apply + outputs: each wave's lanes 0..15 handle its 16 nodes ----
    if (ln == lane && lane < 16) { } // no-op keep structure clear
    if (lane < 16) {
        int m = w * 16 + lane;
        long gi = (long)b * Nn + n0 + m;
        long pk = (long)b * Kk + widx[m];
        float mkv = wmask[m];
        float xv[3], yv[3], xiv[3];
        #pragma unroll
        for (int j = 0; j < 3; ++j) {
            xiv[j] = sc1[m][j];
            float sc = fmaxf(s_k[pk * 3 + j], 1e-8f);
            xv[j] = xiv[j] * sc;
        }
        #pragma unroll
        for (int i = 0; i < 3; ++i) {
            float a = R_k[pk * 9 + i * 3 + 0] * xv[0]
                    + R_k[pk * 9 + i * 3 + 1] * xv[1]
                    + R_k[pk * 9 + i * 3 + 2] * xv[2]
                    + mu_k[pk * 3 + i];
            yv[i] = a * mkv * 10.f;
        }
        float* o0 = out;
        float* o1 = out + (long)Bb * Nn * 3;
        float* o2 = out + (long)Bb * Nn * 6;
        #pragma unroll
        for (int j = 0; j < 3; ++j) { o0[gi * 3 + j] = xiv[j]; o1[gi * 3 + j] = yv[j]; }
        o2[gi] = wpos[m];
    }
}

extern "C" void kernel_launch(void* const* d_in, const int* in_sizes, int n_in,
                              void* d_out, int out_size, void* d_ws, size_t ws_size,
                              hipStream_t stream) {
    const float* s_parent = (const float*)d_in[0];
    const float* mu_k     = (const float*)d_in[1];
    const float* R_k      = (const float*)d_in[2];
    const float* s_k      = (const float*)d_in[3];
    const int*   a_idx    = (const int*)  d_in[4];
    const float* node_mask= (const float*)d_in[5];
    const float* pos01    = (const float*)d_in[6];
    const float* pos_w    = (const float*)d_in[7];
    const float* pos_b    = (const float*)d_in[8];
    const float* q_ln_g   = (const float*)d_in[9];
    const float* q_ln_b   = (const float*)d_in[10];
    const float* q_w1     = (const float*)d_in[11];
    const float* q_b1     = (const float*)d_in[12];
    const float* q_w2     = (const float*)d_in[13];
    const float* q_b2     = (const float*)d_in[14];
    const float* m_ln_g   = (const float*)d_in[15];
    const float* m_ln_b   = (const float*)d_in[16];
    const float* m_w1     = (const float*)d_in[17];
    const float* m_b1     = (const float*)d_in[18];
    const float* m_w2     = (const float*)d_in[19];
    const float* m_b2     = (const float*)d_in[20];
    const float* m_w3     = (const float*)d_in[21];
    const float* m_b3     = (const float*)d_in[22];

    short* wsb = (short*)d_ws;

    conv_w<<<(W_TOTAL + 255) / 256, 256, 0, stream>>>(
        pos_w, q_w1, q_w2, m_w1, m_w2, m_w3, wsb);

    int blocks = (Bb * Nn) / MB;  // 1024
    upxi64<<<blocks, 256, 0, stream>>>(
        s_parent, mu_k, R_k, s_k, a_idx, node_mask, pos01,
        pos_b, q_ln_g, q_ln_b, q_b1, q_b2,
        m_ln_g, m_ln_b, m_b1, m_b2, m_b3,
        wsb, (float*)d_out);
}

// Round 5
// 257.181 us; speedup vs baseline: 2.3421x; 1.2322x over previous
//
#include <hip/hip_runtime.h>
#include <math.h>

#define C 384
#define NF 16
#define H 256
#define Bb 4
#define Kk 2048
#define Nn 16384
#define MB 64           // nodes per block (4 m-tiles)
#define LDA 392         // act row stride in shorts

typedef __attribute__((ext_vector_type(8))) short bf16x8;
typedef __attribute__((ext_vector_type(4))) float f32x4;

// ws layout (shorts), fragment-linear: [ntile][kchunk][ln(16)][kq(32)]
#define POS_OFF 0            // pos_w  F=384 K=32
#define Q1_OFF  12288        // q_w1   F=384 K=384
#define Q2_OFF  159744       // q_w2   F=384 K=384
#define M1_OFF  307200       // m_w1   F=256 K=384
#define M2_OFF  405504       // m_w2   F=256 K=256
#define M3_OFF  471040       // m_w3   F=16(pad) K=256
#define W_TOTAL 475136

__device__ inline short f2bf(float x) {
    union { float f; unsigned u; } v; v.f = x;
    unsigned r = (v.u + 0x7FFFu + ((v.u >> 16) & 1u)) >> 16;
    return (short)r;
}
__device__ inline float bf2f(short s) {
    union { unsigned u; float f; } v; v.u = ((unsigned)(unsigned short)s) << 16;
    return v.f;
}

// ---- weight f32->bf16 + fragment-linear swizzle ----
// dest index t within matrix: chunk=t>>9, r=t&511, ln=r>>5, kq=r&31
// ntg=chunk/(K/32), kk=chunk%(K/32); src = (ntg*16+ln)*K + kk*32+kq
__global__ __launch_bounds__(256) void conv_w(
    const float* __restrict__ pos_w, const float* __restrict__ q_w1,
    const float* __restrict__ q_w2,  const float* __restrict__ m_w1,
    const float* __restrict__ m_w2,  const float* __restrict__ m_w3,
    short* __restrict__ ws)
{
    int i = blockIdx.x * 256 + threadIdx.x;
    if (i >= W_TOTAL) return;
    const float* src; int off, K;
    if      (i < Q1_OFF) { src = pos_w; off = POS_OFF; K = 32; }
    else if (i < Q2_OFF) { src = q_w1;  off = Q1_OFF;  K = 384; }
    else if (i < M1_OFF) { src = q_w2;  off = Q2_OFF;  K = 384; }
    else if (i < M2_OFF) { src = m_w1;  off = M1_OFF;  K = 384; }
    else if (i < M3_OFF) { src = m_w2;  off = M2_OFF;  K = 256; }
    else                 { src = m_w3;  off = M3_OFF;  K = 256; }
    int t = i - off;
    int chunk = t >> 9, r = t & 511;
    int ln = r >> 5, kq = r & 31;
    int NKm = K >> 5;
    int ntg = chunk / NKm, kk = chunk - ntg * NKm;
    int f = ntg * 16 + ln, k = kk * 32 + kq;
    float v;
    if (off == M3_OFF) v = (f < 3) ? m_w3[f * 256 + k] : 0.f;
    else               v = src[(size_t)f * K + k];
    ws[i] = f2bf(v);
}

// LN apply over 384-wide rows; per-wave stat partials already in sc1/sc2.
__device__ __attribute__((always_inline)) inline void ln_apply(
    short (*__restrict__ xs)[LDA], const float* __restrict__ g,
    const float* __restrict__ bb,
    float (*__restrict__ sc1)[4], float (*__restrict__ sc2)[4], int tid)
{
    int m = tid >> 2, j = tid & 3;
    float s1 = sc1[m][0] + sc1[m][1] + sc1[m][2] + sc1[m][3];
    float s2 = sc2[m][0] + sc2[m][1] + sc2[m][2] + sc2[m][3];
    float mean = s1 * (1.f / 384.f);
    float var  = s2 * (1.f / 384.f) - mean * mean;
    float rstd = rsqrtf(var + 1e-5f);
    int c0 = j * 96;
    #pragma unroll
    for (int i = 0; i < 12; ++i) {
        int cc = c0 + i * 8;
        bf16x8 v8 = *(bf16x8*)&xs[m][cc];
        bf16x8 o8;
        #pragma unroll
        for (int e = 0; e < 8; ++e) {
            float v = (bf2f(v8[e]) - mean) * rstd * g[cc + e] + bb[cc + e];
            o8[e] = f2bf(v);
        }
        *(bf16x8*)&xs[m][cc] = o8;
    }
}

// In-place FC layer, 2-deep software-pipelined k-loop over fragment-linear W.
template<int K, int NT, bool SILU, bool MASK, bool STATS>
__device__ __attribute__((always_inline)) inline void layer_ip(
    const short* __restrict__ W, const float* __restrict__ bias, int FB,
    short (*__restrict__ xs)[LDA],
    float (*__restrict__ sc1)[4], float (*__restrict__ sc2)[4],
    const float* __restrict__ wmask, int w, int q, int ln)
{
    constexpr int NK = K / 32;   // 12 or 8 (even)
    const short* bp[NT];
    #pragma unroll
    for (int nt = 0; nt < NT; ++nt)
        bp[nt] = W + ((size_t)(FB / 16 + nt) * NK) * 512 + ln * 32 + q * 8;

    f32x4 acc[4][NT];
    #pragma unroll
    for (int mt = 0; mt < 4; ++mt)
        #pragma unroll
        for (int nt = 0; nt < NT; ++nt)
            acc[mt][nt] = (f32x4){0.f, 0.f, 0.f, 0.f};

    bf16x8 b0[NT], b1[NT], a0[4], a1[4];
    #pragma unroll
    for (int nt = 0; nt < NT; ++nt) b0[nt] = *(const bf16x8*)(bp[nt]);
    #pragma unroll
    for (int mt = 0; mt < 4; ++mt) a0[mt] = *(const bf16x8*)&xs[mt * 16 + ln][q * 8];

    #pragma unroll
    for (int kc = 0; kc < NK; kc += 2) {
        // prefetch kc+1
        #pragma unroll
        for (int nt = 0; nt < NT; ++nt) b1[nt] = *(const bf16x8*)(bp[nt] + (kc + 1) * 512);
        #pragma unroll
        for (int mt = 0; mt < 4; ++mt) a1[mt] = *(const bf16x8*)&xs[mt * 16 + ln][(kc + 1) * 32 + q * 8];
        // MFMA on kc
        #pragma unroll
        for (int nt = 0; nt < NT; ++nt)
            #pragma unroll
            for (int mt = 0; mt < 4; ++mt)
                acc[mt][nt] = __builtin_amdgcn_mfma_f32_16x16x32_bf16(a0[mt], b0[nt], acc[mt][nt], 0, 0, 0);
        // prefetch kc+2
        if (kc + 2 < NK) {
            #pragma unroll
            for (int nt = 0; nt < NT; ++nt) b0[nt] = *(const bf16x8*)(bp[nt] + (kc + 2) * 512);
            #pragma unroll
            for (int mt = 0; mt < 4; ++mt) a0[mt] = *(const bf16x8*)&xs[mt * 16 + ln][(kc + 2) * 32 + q * 8];
        }
        // MFMA on kc+1
        #pragma unroll
        for (int nt = 0; nt < NT; ++nt)
            #pragma unroll
            for (int mt = 0; mt < 4; ++mt)
                acc[mt][nt] = __builtin_amdgcn_mfma_f32_16x16x32_bf16(a1[mt], b1[nt], acc[mt][nt], 0, 0, 0);
    }
    __syncthreads();   // all reads of xs complete before any in-place write

    float s1[4][4], s2[4][4];
    if (STATS) {
        #pragma unroll
        for (int mt = 0; mt < 4; ++mt)
            #pragma unroll
            for (int r = 0; r < 4; ++r) { s1[mt][r] = 0.f; s2[mt][r] = 0.f; }
    }
    #pragma unroll
    for (int nt = 0; nt < NT; ++nt) {
        const int f = FB + nt * 16 + ln;
        float bv = bias[f];
        #pragma unroll
        for (int mt = 0; mt < 4; ++mt) {
            #pragma unroll
            for (int r = 0; r < 4; ++r) {
                int m = mt * 16 + q * 4 + r;
                float v = acc[mt][nt][r] + bv;
                if (SILU) v = v / (1.f + __expf(-v));
                if (MASK) v *= wmask[m];
                if (STATS) { s1[mt][r] += v; s2[mt][r] += v * v; }
                xs[m][f] = f2bf(v);
            }
        }
    }
    if (STATS) {
        #pragma unroll
        for (int d = 1; d < 16; d <<= 1) {
            #pragma unroll
            for (int mt = 0; mt < 4; ++mt)
                #pragma unroll
                for (int r = 0; r < 4; ++r) {
                    s1[mt][r] += __shfl_xor(s1[mt][r], d);
                    s2[mt][r] += __shfl_xor(s2[mt][r], d);
                }
        }
        if (ln == 0) {
            #pragma unroll
            for (int mt = 0; mt < 4; ++mt)
                #pragma unroll
                for (int r = 0; r < 4; ++r) {
                    int m = mt * 16 + q * 4 + r;
                    sc1[m][w] = s1[mt][r];
                    sc2[m][w] = s2[mt][r];
                }
        }
    }
    __syncthreads();   // writes visible before next layer reads
}

__global__ __launch_bounds__(256, 2) void upxi64(
    const float* __restrict__ s_parent, const float* __restrict__ mu_k,
    const float* __restrict__ R_k,      const float* __restrict__ s_k,
    const int*   __restrict__ a_idx,    const float* __restrict__ node_mask,
    const float* __restrict__ pos01,
    const float* __restrict__ pos_b,
    const float* __restrict__ q_ln_g,   const float* __restrict__ q_ln_b,
    const float* __restrict__ q_b1,     const float* __restrict__ q_b2,
    const float* __restrict__ m_ln_g,   const float* __restrict__ m_ln_b,
    const float* __restrict__ m_b1,     const float* __restrict__ m_b2,
    const float* __restrict__ m_b3,
    const short* __restrict__ wsb,
    float* __restrict__ out)
{
    __shared__ short xs[MB][LDA];
    __shared__ float sc1[MB][4];
    __shared__ float sc2[MB][4];
    __shared__ float wmask[MB], wpos[MB];
    __shared__ int   widx[MB];

    const int tid  = threadIdx.x;
    const int w    = tid >> 6;
    const int lane = tid & 63;
    const int q    = lane >> 4;
    const int ln   = lane & 15;

    const int g0 = blockIdx.x * MB;
    const int b  = g0 / Nn;
    const int n0 = g0 % Nn;

    if (tid < MB) {
        int gi = b * Nn + n0 + tid;
        int idx = a_idx[gi];
        widx[tid]  = min(max(idx, 0), Kk - 1);
        wmask[tid] = node_mask[gi];
        wpos[tid]  = pos01[gi];
    }
    __syncthreads();

    const float* gbase = s_parent + (long)b * Kk * C;

    // ---- pos layer: A built in registers (sincos), +pos_b, *mask, +gather, stats ----
    {
        const short* pos_wb = wsb + POS_OFF;
        const bool use_sin = (q < 2);
        const int kb = (q & 1) * 8;
        bf16x8 a[4];
        #pragma unroll
        for (int mt = 0; mt < 4; ++mt) {
            float p = wpos[mt * 16 + ln];
            #pragma unroll
            for (int e = 0; e < 8; ++e) {
                float fr = (float)(1 << (kb + e)) * 3.14159265358979323846f;
                float sv, cv;
                __sincosf(p * fr, &sv, &cv);
                a[mt][e] = f2bf(use_sin ? sv : cv);
            }
        }
        f32x4 acc[4][6];
        #pragma unroll
        for (int mt = 0; mt < 4; ++mt)
            #pragma unroll
            for (int nt = 0; nt < 6; ++nt)
                acc[mt][nt] = (f32x4){0.f, 0.f, 0.f, 0.f};
        #pragma unroll
        for (int nt = 0; nt < 6; ++nt) {
            bf16x8 bfr = *(const bf16x8*)&pos_wb[(w * 6 + nt) * 512 + ln * 32 + q * 8];
            #pragma unroll
            for (int mt = 0; mt < 4; ++mt)
                acc[mt][nt] = __builtin_amdgcn_mfma_f32_16x16x32_bf16(a[mt], bfr, acc[mt][nt], 0, 0, 0);
        }
        float s1[4][4], s2[4][4];
        #pragma unroll
        for (int mt = 0; mt < 4; ++mt)
            #pragma unroll
            for (int r = 0; r < 4; ++r) { s1[mt][r] = 0.f; s2[mt][r] = 0.f; }
        #pragma unroll
        for (int nt = 0; nt < 6; ++nt) {
            int f = w * 96 + nt * 16 + ln;
            float pbv = pos_b[f];
            #pragma unroll
            for (int mt = 0; mt < 4; ++mt) {
                #pragma unroll
                for (int r = 0; r < 4; ++r) {
                    int m = mt * 16 + q * 4 + r;
                    float v = (acc[mt][nt][r] + pbv) * wmask[m]
                            + gbase[(long)widx[m] * C + f];
                    s1[mt][r] += v; s2[mt][r] += v * v;
                    xs[m][f] = f2bf(v);
                }
            }
        }
        #pragma unroll
        for (int d = 1; d < 16; d <<= 1) {
            #pragma unroll
            for (int mt = 0; mt < 4; ++mt)
                #pragma unroll
                for (int r = 0; r < 4; ++r) {
                    s1[mt][r] += __shfl_xor(s1[mt][r], d);
                    s2[mt][r] += __shfl_xor(s2[mt][r], d);
                }
        }
        if (ln == 0) {
            #pragma unroll
            for (int mt = 0; mt < 4; ++mt)
                #pragma unroll
                for (int r = 0; r < 4; ++r) {
                    int m = mt * 16 + q * 4 + r;
                    sc1[m][w] = s1[mt][r];
                    sc2[m][w] = s2[mt][r];
                }
        }
    }
    __syncthreads();

    ln_apply(xs, q_ln_g, q_ln_b, sc1, sc2, tid);
    __syncthreads();

    layer_ip<384, 6, true,  false, false>(wsb + Q1_OFF, q_b1, w * 96, xs, sc1, sc2, wmask, w, q, ln);
    layer_ip<384, 6, false, true,  true >(wsb + Q2_OFF, q_b2, w * 96, xs, sc1, sc2, wmask, w, q, ln);

    ln_apply(xs, m_ln_g, m_ln_b, sc1, sc2, tid);
    __syncthreads();

    layer_ip<384, 4, true, false, false>(wsb + M1_OFF, m_b1, w * 64, xs, sc1, sc2, wmask, w, q, ln);
    layer_ip<256, 4, true, false, false>(wsb + M2_OFF, m_b2, w * 64, xs, sc1, sc2, wmask, w, q, ln);

    // ---- tail: 256->3 MFMA (wave w owns m-tile w), tanh*1.5 ----
    {
        const short* W3 = wsb + M3_OFF;
        f32x4 a3 = (f32x4){0.f, 0.f, 0.f, 0.f};
        #pragma unroll
        for (int kc = 0; kc < 8; ++kc) {
            bf16x8 a  = *(const bf16x8*)&xs[w * 16 + ln][kc * 32 + q * 8];
            bf16x8 bf = *(const bf16x8*)(W3 + kc * 512 + ln * 32 + q * 8);
            a3 = __builtin_amdgcn_mfma_f32_16x16x32_bf16(a, bf, a3, 0, 0, 0);
        }
        if (ln < 3) {
            float bv = m_b3[ln];
            #pragma unroll
            for (int r = 0; r < 4; ++r) {
                int m = w * 16 + q * 4 + r;
                float v = (a3[r] + bv) * wmask[m];
                sc1[m][ln] = tanhf(v) * 1.5f;
            }
        }
    }

    // ---- rigid apply + outputs ----
    if (lane < 16) {
        int m = w * 16 + lane;
        long gi = (long)b * Nn + n0 + m;
        long pk = (long)b * Kk + widx[m];
        float mkv = wmask[m];
        float xv[3], yv[3], xiv[3];
        #pragma unroll
        for (int j = 0; j < 3; ++j) {
            xiv[j] = sc1[m][j];
            float sc = fmaxf(s_k[pk * 3 + j], 1e-8f);
            xv[j] = xiv[j] * sc;
        }
        #pragma unroll
        for (int i = 0; i < 3; ++i) {
            float a = R_k[pk * 9 + i * 3 + 0] * xv[0]
                    + R_k[pk * 9 + i * 3 + 1] * xv[1]
                    + R_k[pk * 9 + i * 3 + 2] * xv[2]
                    + mu_k[pk * 3 + i];
            yv[i] = a * mkv * 10.f;
        }
        float* o0 = out;
        float* o1 = out + (long)Bb * Nn * 3;
        float* o2 = out + (long)Bb * Nn * 6;
        #pragma unroll
        for (int j = 0; j < 3; ++j) { o0[gi * 3 + j] = xiv[j]; o1[gi * 3 + j] = yv[j]; }
        o2[gi] = wpos[m];
    }
}

extern "C" void kernel_launch(void* const* d_in, const int* in_sizes, int n_in,
                              void* d_out, int out_size, void* d_ws, size_t ws_size,
                              hipStream_t stream) {
    const float* s_parent = (const float*)d_in[0];
    const float* mu_k     = (const float*)d_in[1];
    const float* R_k      = (const float*)d_in[2];
    const float* s_k      = (const float*)d_in[3];
    const int*   a_idx    = (const int*)  d_in[4];
    const float* node_mask= (const float*)d_in[5];
    const float* pos01    = (const float*)d_in[6];
    const float* pos_w    = (const float*)d_in[7];
    const float* pos_b    = (const float*)d_in[8];
    const float* q_ln_g   = (const float*)d_in[9];
    const float* q_ln_b   = (const float*)d_in[10];
    const float* q_w1     = (const float*)d_in[11];
    const float* q_b1     = (const float*)d_in[12];
    const float* q_w2     = (const float*)d_in[13];
    const float* q_b2     = (const float*)d_in[14];
    const float* m_ln_g   = (const float*)d_in[15];
    const float* m_ln_b   = (const float*)d_in[16];
    const float* m_w1     = (const float*)d_in[17];
    const float* m_b1     = (const float*)d_in[18];
    const float* m_w2     = (const float*)d_in[19];
    const float* m_b2     = (const float*)d_in[20];
    const float* m_w3     = (const float*)d_in[21];
    const float* m_b3     = (const float*)d_in[22];

    short* wsb = (short*)d_ws;

    conv_w<<<(W_TOTAL + 255) / 256, 256, 0, stream>>>(
        pos_w, q_w1, q_w2, m_w1, m_w2, m_w3, wsb);

    int blocks = (Bb * Nn) / MB;  // 1024
    upxi64<<<blocks, 256, 0, stream>>>(
        s_parent, mu_k, R_k, s_k, a_idx, node_mask, pos01,
        pos_b, q_ln_g, q_ln_b, q_b1, q_b2,
        m_ln_g, m_ln_b, m_b1, m_b2, m_b3,
        wsb, (float*)d_out);
}

// Round 6
// 238.766 us; speedup vs baseline: 2.5227x; 1.0771x over previous
//
#include <hip/hip_runtime.h>
#include <hip/hip_bf16.h>
#include <math.h>

#define C 384
#define NF 16
#define H 256
#define Bb 4
#define Kk 2048
#define Nn 16384
#define MB 64           // nodes per block (4 m-tiles)
#define LDA 392         // act row stride in shorts

typedef __attribute__((ext_vector_type(8))) short bf16x8;
typedef __attribute__((ext_vector_type(4))) float f32x4;

// ws layout (shorts), fragment-linear: [ntile][kchunk][ln(16)][kq(32)]
#define POS_OFF 0            // pos_w  F=384 K=32
#define Q1_OFF  12288        // q_w1   F=384 K=384
#define Q2_OFF  159744       // q_w2   F=384 K=384
#define M1_OFF  307200       // m_w1   F=256 K=384
#define M2_OFF  405504       // m_w2   F=256 K=256
#define M3_OFF  471040       // m_w3   F=16(pad) K=256
#define W_TOTAL 475136

__device__ __attribute__((always_inline)) inline short f2bf(float x) {
    return __builtin_bit_cast(short, __float2bfloat16(x));   // native cvt, RNE
}
__device__ __attribute__((always_inline)) inline float bf2f(short s) {
    return __bfloat162float(__builtin_bit_cast(__hip_bfloat16, s));
}
__device__ __attribute__((always_inline)) inline float silu(float v) {
    return v * __builtin_amdgcn_rcpf(1.f + __expf(-v));      // approx rcp, ~1ulp
}

// ---- weight f32->bf16 + fragment-linear swizzle ----
__global__ __launch_bounds__(256) void conv_w(
    const float* __restrict__ pos_w, const float* __restrict__ q_w1,
    const float* __restrict__ q_w2,  const float* __restrict__ m_w1,
    const float* __restrict__ m_w2,  const float* __restrict__ m_w3,
    short* __restrict__ ws)
{
    int i = blockIdx.x * 256 + threadIdx.x;
    if (i >= W_TOTAL) return;
    const float* src; int off, K;
    if      (i < Q1_OFF) { src = pos_w; off = POS_OFF; K = 32; }
    else if (i < Q2_OFF) { src = q_w1;  off = Q1_OFF;  K = 384; }
    else if (i < M1_OFF) { src = q_w2;  off = Q2_OFF;  K = 384; }
    else if (i < M2_OFF) { src = m_w1;  off = M1_OFF;  K = 384; }
    else if (i < M3_OFF) { src = m_w2;  off = M2_OFF;  K = 256; }
    else                 { src = m_w3;  off = M3_OFF;  K = 256; }
    int t = i - off;
    int chunk = t >> 9, r = t & 511;
    int ln = r >> 5, kq = r & 31;
    int NKm = K >> 5;
    int ntg = chunk / NKm, kk = chunk - ntg * NKm;
    int f = ntg * 16 + ln, k = kk * 32 + kq;
    float v;
    if (off == M3_OFF) v = (f < 3) ? m_w3[f * 256 + k] : 0.f;
    else               v = src[(size_t)f * K + k];
    ws[i] = f2bf(v);
}

// LN apply over 384-wide rows; per-wave stat partials already in sc1/sc2.
__device__ __attribute__((always_inline)) inline void ln_apply(
    short (*__restrict__ xs)[LDA], const float* __restrict__ g,
    const float* __restrict__ bb,
    float (*__restrict__ sc1)[4], float (*__restrict__ sc2)[4], int tid)
{
    int m = tid >> 2, j = tid & 3;
    float s1 = sc1[m][0] + sc1[m][1] + sc1[m][2] + sc1[m][3];
    float s2 = sc2[m][0] + sc2[m][1] + sc2[m][2] + sc2[m][3];
    float mean = s1 * (1.f / 384.f);
    float var  = s2 * (1.f / 384.f) - mean * mean;
    float rstd = rsqrtf(var + 1e-5f);
    int c0 = j * 96;
    #pragma unroll
    for (int i = 0; i < 12; ++i) {
        int cc = c0 + i * 8;
        bf16x8 v8 = *(bf16x8*)&xs[m][cc];
        bf16x8 o8;
        #pragma unroll
        for (int e = 0; e < 8; ++e) {
            float v = (bf2f(v8[e]) - mean) * rstd * g[cc + e] + bb[cc + e];
            o8[e] = f2bf(v);
        }
        *(bf16x8*)&xs[m][cc] = o8;
    }
}

// In-place FC layer, 2-deep pipelined k-loop over fragment-linear W.
// bin: prefetched first-chunk B for THIS layer; on exit holds next layer's.
template<int K, int NT, int NTN, int KN, bool SILU_, bool MASK, bool STATS>
__device__ __attribute__((always_inline)) inline void layer_ip(
    const short* __restrict__ W, const float* __restrict__ bias, int FB,
    const short* __restrict__ Wn, int FBn,
    bf16x8 (&bin)[6],
    short (*__restrict__ xs)[LDA],
    float (*__restrict__ sc1)[4], float (*__restrict__ sc2)[4],
    const float* __restrict__ wmask, int w, int q, int ln)
{
    constexpr int NK = K / 32;
    const short* bp[NT];
    #pragma unroll
    for (int nt = 0; nt < NT; ++nt)
        bp[nt] = W + ((size_t)(FB / 16 + nt) * NK) * 512 + ln * 32 + q * 8;

    f32x4 acc[4][NT];
    #pragma unroll
    for (int mt = 0; mt < 4; ++mt)
        #pragma unroll
        for (int nt = 0; nt < NT; ++nt)
            acc[mt][nt] = (f32x4){0.f, 0.f, 0.f, 0.f};

    bf16x8 b0[NT], b1[NT], a0[4], a1[4];
    #pragma unroll
    for (int nt = 0; nt < NT; ++nt) b0[nt] = bin[nt];   // prefetched first chunk
    #pragma unroll
    for (int mt = 0; mt < 4; ++mt) a0[mt] = *(const bf16x8*)&xs[mt * 16 + ln][q * 8];

    #pragma unroll
    for (int kc = 0; kc < NK; kc += 2) {
        #pragma unroll
        for (int nt = 0; nt < NT; ++nt) b1[nt] = *(const bf16x8*)(bp[nt] + (kc + 1) * 512);
        #pragma unroll
        for (int mt = 0; mt < 4; ++mt) a1[mt] = *(const bf16x8*)&xs[mt * 16 + ln][(kc + 1) * 32 + q * 8];
        #pragma unroll
        for (int nt = 0; nt < NT; ++nt)
            #pragma unroll
            for (int mt = 0; mt < 4; ++mt)
                acc[mt][nt] = __builtin_amdgcn_mfma_f32_16x16x32_bf16(a0[mt], b0[nt], acc[mt][nt], 0, 0, 0);
        if (kc + 2 < NK) {
            #pragma unroll
            for (int nt = 0; nt < NT; ++nt) b0[nt] = *(const bf16x8*)(bp[nt] + (kc + 2) * 512);
            #pragma unroll
            for (int mt = 0; mt < 4; ++mt) a0[mt] = *(const bf16x8*)&xs[mt * 16 + ln][(kc + 2) * 32 + q * 8];
        }
        #pragma unroll
        for (int nt = 0; nt < NT; ++nt)
            #pragma unroll
            for (int mt = 0; mt < 4; ++mt)
                acc[mt][nt] = __builtin_amdgcn_mfma_f32_16x16x32_bf16(a1[mt], b1[nt], acc[mt][nt], 0, 0, 0);
    }

    // prefetch NEXT layer's first k-chunk (weights only; no xs hazard) —
    // in flight across both barriers + epilogue.
    #pragma unroll
    for (int nt = 0; nt < NTN; ++nt)
        bin[nt] = *(const bf16x8*)(Wn + ((size_t)(FBn / 16 + nt) * (KN / 32)) * 512 + ln * 32 + q * 8);

    __syncthreads();   // all reads of xs complete before any in-place write

    float s1[4][4], s2[4][4];
    if (STATS) {
        #pragma unroll
        for (int mt = 0; mt < 4; ++mt)
            #pragma unroll
            for (int r = 0; r < 4; ++r) { s1[mt][r] = 0.f; s2[mt][r] = 0.f; }
    }
    #pragma unroll
    for (int nt = 0; nt < NT; ++nt) {
        const int f = FB + nt * 16 + ln;
        float bv = bias[f];
        #pragma unroll
        for (int mt = 0; mt < 4; ++mt) {
            #pragma unroll
            for (int r = 0; r < 4; ++r) {
                int m = mt * 16 + q * 4 + r;
                float v = acc[mt][nt][r] + bv;
                if (SILU_) v = silu(v);
                if (MASK) v *= wmask[m];
                if (STATS) { s1[mt][r] += v; s2[mt][r] += v * v; }
                xs[m][f] = f2bf(v);
            }
        }
    }
    if (STATS) {
        #pragma unroll
        for (int d = 1; d < 16; d <<= 1) {
            #pragma unroll
            for (int mt = 0; mt < 4; ++mt)
                #pragma unroll
                for (int r = 0; r < 4; ++r) {
                    s1[mt][r] += __shfl_xor(s1[mt][r], d);
                    s2[mt][r] += __shfl_xor(s2[mt][r], d);
                }
        }
        if (ln == 0) {
            #pragma unroll
            for (int mt = 0; mt < 4; ++mt)
                #pragma unroll
                for (int r = 0; r < 4; ++r) {
                    int m = mt * 16 + q * 4 + r;
                    sc1[m][w] = s1[mt][r];
                    sc2[m][w] = s2[mt][r];
                }
        }
    }
    __syncthreads();   // writes visible before next layer reads
}

__global__ __launch_bounds__(256, 2) void upxi64(
    const float* __restrict__ s_parent, const float* __restrict__ mu_k,
    const float* __restrict__ R_k,      const float* __restrict__ s_k,
    const int*   __restrict__ a_idx,    const float* __restrict__ node_mask,
    const float* __restrict__ pos01,
    const float* __restrict__ pos_b,
    const float* __restrict__ q_ln_g,   const float* __restrict__ q_ln_b,
    const float* __restrict__ q_b1,     const float* __restrict__ q_b2,
    const float* __restrict__ m_ln_g,   const float* __restrict__ m_ln_b,
    const float* __restrict__ m_b1,     const float* __restrict__ m_b2,
    const float* __restrict__ m_b3,
    const short* __restrict__ wsb,
    float* __restrict__ out)
{
    __shared__ short xs[MB][LDA];
    __shared__ float sc1[MB][4];
    __shared__ float sc2[MB][4];
    __shared__ float wmask[MB], wpos[MB];
    __shared__ int   widx[MB];

    const int tid  = threadIdx.x;
    const int w    = tid >> 6;
    const int lane = tid & 63;
    const int q    = lane >> 4;
    const int ln   = lane & 15;

    const int g0 = blockIdx.x * MB;
    const int b  = g0 / Nn;
    const int n0 = g0 % Nn;

    // prefetch Q1 first k-chunk immediately (hidden under scalars+sincos+pos)
    bf16x8 bin[6];
    #pragma unroll
    for (int nt = 0; nt < 6; ++nt)
        bin[nt] = *(const bf16x8*)(wsb + Q1_OFF + ((size_t)(w * 6 + nt) * 12) * 512 + ln * 32 + q * 8);

    if (tid < MB) {
        int gi = b * Nn + n0 + tid;
        int idx = a_idx[gi];
        widx[tid]  = min(max(idx, 0), Kk - 1);
        wmask[tid] = node_mask[gi];
        wpos[tid]  = pos01[gi];
    }
    __syncthreads();

    const float* gbase = s_parent + (long)b * Kk * C;

    // ---- pos layer: A in registers (sincos), +pos_b, *mask, +gather, stats ----
    {
        const short* pos_wb = wsb + POS_OFF;
        const bool use_sin = (q < 2);
        const int kb = (q & 1) * 8;
        bf16x8 a[4];
        #pragma unroll
        for (int mt = 0; mt < 4; ++mt) {
            float p = wpos[mt * 16 + ln];
            #pragma unroll
            for (int e = 0; e < 8; ++e) {
                float fr = (float)(1 << (kb + e)) * 3.14159265358979323846f;
                float sv, cv;
                __sincosf(p * fr, &sv, &cv);
                a[mt][e] = f2bf(use_sin ? sv : cv);
            }
        }
        f32x4 acc[4][6];
        #pragma unroll
        for (int mt = 0; mt < 4; ++mt)
            #pragma unroll
            for (int nt = 0; nt < 6; ++nt)
                acc[mt][nt] = (f32x4){0.f, 0.f, 0.f, 0.f};
        #pragma unroll
        for (int nt = 0; nt < 6; ++nt) {
            bf16x8 bfr = *(const bf16x8*)&pos_wb[(w * 6 + nt) * 512 + ln * 32 + q * 8];
            #pragma unroll
            for (int mt = 0; mt < 4; ++mt)
                acc[mt][nt] = __builtin_amdgcn_mfma_f32_16x16x32_bf16(a[mt], bfr, acc[mt][nt], 0, 0, 0);
        }
        float s1[4][4], s2[4][4];
        #pragma unroll
        for (int mt = 0; mt < 4; ++mt)
            #pragma unroll
            for (int r = 0; r < 4; ++r) { s1[mt][r] = 0.f; s2[mt][r] = 0.f; }
        #pragma unroll
        for (int nt = 0; nt < 6; ++nt) {
            int f = w * 96 + nt * 16 + ln;
            float pbv = pos_b[f];
            #pragma unroll
            for (int mt = 0; mt < 4; ++mt) {
                #pragma unroll
                for (int r = 0; r < 4; ++r) {
                    int m = mt * 16 + q * 4 + r;
                    float v = (acc[mt][nt][r] + pbv) * wmask[m]
                            + gbase[(long)widx[m] * C + f];
                    s1[mt][r] += v; s2[mt][r] += v * v;
                    xs[m][f] = f2bf(v);
                }
            }
        }
        #pragma unroll
        for (int d = 1; d < 16; d <<= 1) {
            #pragma unroll
            for (int mt = 0; mt < 4; ++mt)
                #pragma unroll
                for (int r = 0; r < 4; ++r) {
                    s1[mt][r] += __shfl_xor(s1[mt][r], d);
                    s2[mt][r] += __shfl_xor(s2[mt][r], d);
                }
        }
        if (ln == 0) {
            #pragma unroll
            for (int mt = 0; mt < 4; ++mt)
                #pragma unroll
                for (int r = 0; r < 4; ++r) {
                    int m = mt * 16 + q * 4 + r;
                    sc1[m][w] = s1[mt][r];
                    sc2[m][w] = s2[mt][r];
                }
        }
    }
    __syncthreads();

    ln_apply(xs, q_ln_g, q_ln_b, sc1, sc2, tid);
    __syncthreads();

    layer_ip<384, 6, 6, 384, true,  false, false>(wsb + Q1_OFF, q_b1, w * 96,
        wsb + Q2_OFF, w * 96, bin, xs, sc1, sc2, wmask, w, q, ln);
    layer_ip<384, 6, 4, 384, false, true,  true >(wsb + Q2_OFF, q_b2, w * 96,
        wsb + M1_OFF, w * 64, bin, xs, sc1, sc2, wmask, w, q, ln);

    ln_apply(xs, m_ln_g, m_ln_b, sc1, sc2, tid);
    __syncthreads();

    layer_ip<384, 4, 4, 256, true, false, false>(wsb + M1_OFF, m_b1, w * 64,
        wsb + M2_OFF, w * 64, bin, xs, sc1, sc2, wmask, w, q, ln);
    layer_ip<256, 4, 1, 256, true, false, false>(wsb + M2_OFF, m_b2, w * 64,
        wsb + M3_OFF, 0, bin, xs, sc1, sc2, wmask, w, q, ln);

    // ---- tail: 256->3 MFMA (wave w owns m-tile w), tanh*1.5 ----
    {
        const short* W3 = wsb + M3_OFF;
        f32x4 a3 = (f32x4){0.f, 0.f, 0.f, 0.f};
        #pragma unroll
        for (int kc = 0; kc < 8; ++kc) {
            bf16x8 a  = *(const bf16x8*)&xs[w * 16 + ln][kc * 32 + q * 8];
            bf16x8 bf = (kc == 0) ? bin[0]
                      : *(const bf16x8*)(W3 + kc * 512 + ln * 32 + q * 8);
            a3 = __builtin_amdgcn_mfma_f32_16x16x32_bf16(a, bf, a3, 0, 0, 0);
        }
        if (ln < 3) {
            float bv = m_b3[ln];
            #pragma unroll
            for (int r = 0; r < 4; ++r) {
                int m = w * 16 + q * 4 + r;
                float v = (a3[r] + bv) * wmask[m];
                sc1[m][ln] = tanhf(v) * 1.5f;
            }
        }
    }

    // ---- rigid apply + outputs ----
    if (lane < 16) {
        int m = w * 16 + lane;
        long gi = (long)b * Nn + n0 + m;
        long pk = (long)b * Kk + widx[m];
        float mkv = wmask[m];
        float xv[3], yv[3], xiv[3];
        #pragma unroll
        for (int j = 0; j < 3; ++j) {
            xiv[j] = sc1[m][j];
            float sc = fmaxf(s_k[pk * 3 + j], 1e-8f);
            xv[j] = xiv[j] * sc;
        }
        #pragma unroll
        for (int i = 0; i < 3; ++i) {
            float a = R_k[pk * 9 + i * 3 + 0] * xv[0]
                    + R_k[pk * 9 + i * 3 + 1] * xv[1]
                    + R_k[pk * 9 + i * 3 + 2] * xv[2]
                    + mu_k[pk * 3 + i];
            yv[i] = a * mkv * 10.f;
        }
        float* o0 = out;
        float* o1 = out + (long)Bb * Nn * 3;
        float* o2 = out + (long)Bb * Nn * 6;
        #pragma unroll
        for (int j = 0; j < 3; ++j) { o0[gi * 3 + j] = xiv[j]; o1[gi * 3 + j] = yv[j]; }
        o2[gi] = wpos[m];
    }
}

extern "C" void kernel_launch(void* const* d_in, const int* in_sizes, int n_in,
                              void* d_out, int out_size, void* d_ws, size_t ws_size,
                              hipStream_t stream) {
    const float* s_parent = (const float*)d_in[0];
    const float* mu_k     = (const float*)d_in[1];
    const float* R_k      = (const float*)d_in[2];
    const float* s_k      = (const float*)d_in[3];
    const int*   a_idx    = (const int*)  d_in[4];
    const float* node_mask= (const float*)d_in[5];
    const float* pos01    = (const float*)d_in[6];
    const float* pos_w    = (const float*)d_in[7];
    const float* pos_b    = (const float*)d_in[8];
    const float* q_ln_g   = (const float*)d_in[9];
    const float* q_ln_b   = (const float*)d_in[10];
    const float* q_w1     = (const float*)d_in[11];
    const float* q_b1     = (const float*)d_in[12];
    const float* q_w2     = (const float*)d_in[13];
    const float* q_b2     = (const float*)d_in[14];
    const float* m_ln_g   = (const float*)d_in[15];
    const float* m_ln_b   = (const float*)d_in[16];
    const float* m_w1     = (const float*)d_in[17];
    const float* m_b1     = (const float*)d_in[18];
    const float* m_w2     = (const float*)d_in[19];
    const float* m_b2     = (const float*)d_in[20];
    const float* m_w3     = (const float*)d_in[21];
    const float* m_b3     = (const float*)d_in[22];

    short* wsb = (short*)d_ws;

    conv_w<<<(W_TOTAL + 255) / 256, 256, 0, stream>>>(
        pos_w, q_w1, q_w2, m_w1, m_w2, m_w3, wsb);

    int blocks = (Bb * Nn) / MB;  // 1024
    upxi64<<<blocks, 256, 0, stream>>>(
        s_parent, mu_k, R_k, s_k, a_idx, node_mask, pos01,
        pos_b, q_ln_g, q_ln_b, q_b1, q_b2,
        m_ln_g, m_ln_b, m_b1, m_b2, m_b3,
        wsb, (float*)d_out);
}

// Round 7
// 226.360 us; speedup vs baseline: 2.6610x; 1.0548x over previous
//
#include <hip/hip_runtime.h>
#include <hip/hip_bf16.h>
#include <math.h>

#define C 384
#define NF 16
#define H 256
#define Bb 4
#define Kk 2048
#define Nn 16384
#define MB 64           // nodes per block (4 m-tiles)
#define LDA 392         // act row stride in shorts

typedef __attribute__((ext_vector_type(8))) short bf16x8;
typedef __attribute__((ext_vector_type(4))) float f32x4;
typedef __attribute__((ext_vector_type(4))) short s16x4;

// ws layout (shorts), fragment-linear: [ntile][kchunk][ln(16)][kq(32)]
#define POS_OFF 0            // pos_w  F=384 K=32
#define Q1_OFF  12288        // q_w1   F=384 K=384
#define Q2_OFF  159744       // q_w2   F=384 K=384
#define M1_OFF  307200       // m_w1   F=256 K=384
#define M2_OFF  405504       // m_w2   F=256 K=256
#define M3_OFF  471040       // m_w3   F=16(pad) K=256
#define W_TOTAL 475136

__device__ __attribute__((always_inline)) inline short f2bf(float x) {
    return __builtin_bit_cast(short, __float2bfloat16(x));   // native cvt, RNE
}
__device__ __attribute__((always_inline)) inline float bf2f(short s) {
    return __bfloat162float(__builtin_bit_cast(__hip_bfloat16, s));
}
__device__ __attribute__((always_inline)) inline float silu(float v) {
    return v * __builtin_amdgcn_rcpf(1.f + __expf(-v));
}

// ---- weight f32->bf16 + fragment-linear swizzle ----
__global__ __launch_bounds__(256) void conv_w(
    const float* __restrict__ pos_w, const float* __restrict__ q_w1,
    const float* __restrict__ q_w2,  const float* __restrict__ m_w1,
    const float* __restrict__ m_w2,  const float* __restrict__ m_w3,
    short* __restrict__ ws)
{
    int i = blockIdx.x * 256 + threadIdx.x;
    if (i >= W_TOTAL) return;
    const float* src; int off, K;
    if      (i < Q1_OFF) { src = pos_w; off = POS_OFF; K = 32; }
    else if (i < Q2_OFF) { src = q_w1;  off = Q1_OFF;  K = 384; }
    else if (i < M1_OFF) { src = q_w2;  off = Q2_OFF;  K = 384; }
    else if (i < M2_OFF) { src = m_w1;  off = M1_OFF;  K = 384; }
    else if (i < M3_OFF) { src = m_w2;  off = M2_OFF;  K = 256; }
    else                 { src = m_w3;  off = M3_OFF;  K = 256; }
    int t = i - off;
    int chunk = t >> 9, r = t & 511;
    int ln = r >> 5, kq = r & 31;
    int NKm = K >> 5;
    int ntg = chunk / NKm, kk = chunk - ntg * NKm;
    int f = ntg * 16 + ln, k = kk * 32 + kq;
    float v;
    if (off == M3_OFF) v = (f < 3) ? m_w3[f * 256 + k] : 0.f;
    else               v = src[(size_t)f * K + k];
    ws[i] = f2bf(v);
}

// LN apply over 384-wide rows; per-wave stat partials already in sc1/sc2.
__device__ __attribute__((always_inline)) inline void ln_apply(
    short (*__restrict__ xs)[LDA], const float* __restrict__ g,
    const float* __restrict__ bb,
    float (*__restrict__ sc1)[4], float (*__restrict__ sc2)[4], int tid)
{
    int m = tid >> 2, j = tid & 3;
    float s1 = sc1[m][0] + sc1[m][1] + sc1[m][2] + sc1[m][3];
    float s2 = sc2[m][0] + sc2[m][1] + sc2[m][2] + sc2[m][3];
    float mean = s1 * (1.f / 384.f);
    float var  = s2 * (1.f / 384.f) - mean * mean;
    float rstd = rsqrtf(var + 1e-5f);
    int c0 = j * 96;
    #pragma unroll
    for (int i = 0; i < 12; ++i) {
        int cc = c0 + i * 8;
        bf16x8 v8 = *(bf16x8*)&xs[m][cc];
        bf16x8 o8;
        #pragma unroll
        for (int e = 0; e < 8; ++e) {
            float v = (bf2f(v8[e]) - mean) * rstd * g[cc + e] + bb[cc + e];
            o8[e] = f2bf(v);
        }
        *(bf16x8*)&xs[m][cc] = o8;
    }
}

// In-place FC layer, 2-deep pipelined k-loop, TRANSPOSED D (weights as
// A-operand): thread (q,ln) holds D[f=FB+nt*16+q*4+r][m=mt*16+ln].
template<int K, int NT, int NTN, int KN, bool SILU_, bool MASK, bool STATS>
__device__ __attribute__((always_inline)) inline void layer_ip(
    const short* __restrict__ W, const float* __restrict__ bias, int FB,
    const short* __restrict__ Wn, int FBn,
    bf16x8 (&bin)[6],
    short (*__restrict__ xs)[LDA],
    float (*__restrict__ sc1)[4], float (*__restrict__ sc2)[4],
    const float* __restrict__ wmask, int w, int q, int ln)
{
    constexpr int NK = K / 32;
    const short* bp[NT];
    #pragma unroll
    for (int nt = 0; nt < NT; ++nt)
        bp[nt] = W + ((size_t)(FB / 16 + nt) * NK) * 512 + ln * 32 + q * 8;

    f32x4 acc[4][NT];
    #pragma unroll
    for (int mt = 0; mt < 4; ++mt)
        #pragma unroll
        for (int nt = 0; nt < NT; ++nt)
            acc[mt][nt] = (f32x4){0.f, 0.f, 0.f, 0.f};

    bf16x8 b0[NT], b1[NT], a0[4], a1[4];
    #pragma unroll
    for (int nt = 0; nt < NT; ++nt) b0[nt] = bin[nt];
    #pragma unroll
    for (int mt = 0; mt < 4; ++mt) a0[mt] = *(const bf16x8*)&xs[mt * 16 + ln][q * 8];

    #pragma unroll
    for (int kc = 0; kc < NK; kc += 2) {
        #pragma unroll
        for (int nt = 0; nt < NT; ++nt) b1[nt] = *(const bf16x8*)(bp[nt] + (kc + 1) * 512);
        #pragma unroll
        for (int mt = 0; mt < 4; ++mt) a1[mt] = *(const bf16x8*)&xs[mt * 16 + ln][(kc + 1) * 32 + q * 8];
        #pragma unroll
        for (int nt = 0; nt < NT; ++nt)
            #pragma unroll
            for (int mt = 0; mt < 4; ++mt)
                acc[mt][nt] = __builtin_amdgcn_mfma_f32_16x16x32_bf16(b0[nt], a0[mt], acc[mt][nt], 0, 0, 0);
        if (kc + 2 < NK) {
            #pragma unroll
            for (int nt = 0; nt < NT; ++nt) b0[nt] = *(const bf16x8*)(bp[nt] + (kc + 2) * 512);
            #pragma unroll
            for (int mt = 0; mt < 4; ++mt) a0[mt] = *(const bf16x8*)&xs[mt * 16 + ln][(kc + 2) * 32 + q * 8];
        }
        #pragma unroll
        for (int nt = 0; nt < NT; ++nt)
            #pragma unroll
            for (int mt = 0; mt < 4; ++mt)
                acc[mt][nt] = __builtin_amdgcn_mfma_f32_16x16x32_bf16(b1[nt], a1[mt], acc[mt][nt], 0, 0, 0);
    }

    // prefetch NEXT layer's first k-chunk — rides across barriers + epilogue
    #pragma unroll
    for (int nt = 0; nt < NTN; ++nt)
        bin[nt] = *(const bf16x8*)(Wn + ((size_t)(FBn / 16 + nt) * (KN / 32)) * 512 + ln * 32 + q * 8);

    __syncthreads();   // all reads of xs complete before any in-place write

    float mk[4];
    #pragma unroll
    for (int mt = 0; mt < 4; ++mt) mk[mt] = wmask[mt * 16 + ln];

    float s1[4] = {0.f,0.f,0.f,0.f}, s2[4] = {0.f,0.f,0.f,0.f};
    #pragma unroll
    for (int nt = 0; nt < NT; ++nt) {
        const int f0 = FB + nt * 16 + q * 4;
        f32x4 bv = *(const f32x4*)&bias[f0];
        #pragma unroll
        for (int mt = 0; mt < 4; ++mt) {
            s16x4 o4;
            #pragma unroll
            for (int r = 0; r < 4; ++r) {
                float v = acc[mt][nt][r] + bv[r];
                if (SILU_) v = silu(v);
                if (MASK) v *= mk[mt];
                if (STATS) { s1[mt] += v; s2[mt] += v * v; }
                o4[r] = f2bf(v);
            }
            *(s16x4*)&xs[mt * 16 + ln][f0] = o4;
        }
    }
    if (STATS) {
        #pragma unroll
        for (int mt = 0; mt < 4; ++mt) {
            s1[mt] += __shfl_xor(s1[mt], 16); s2[mt] += __shfl_xor(s2[mt], 16);
            s1[mt] += __shfl_xor(s1[mt], 32); s2[mt] += __shfl_xor(s2[mt], 32);
        }
        if (q == 0) {
            #pragma unroll
            for (int mt = 0; mt < 4; ++mt) {
                sc1[mt * 16 + ln][w] = s1[mt];
                sc2[mt * 16 + ln][w] = s2[mt];
            }
        }
    }
    __syncthreads();   // writes visible before next layer reads
}

__global__ __launch_bounds__(256, 2) void upxi64(
    const float* __restrict__ s_parent, const float* __restrict__ mu_k,
    const float* __restrict__ R_k,      const float* __restrict__ s_k,
    const int*   __restrict__ a_idx,    const float* __restrict__ node_mask,
    const float* __restrict__ pos01,
    const float* __restrict__ pos_b,
    const float* __restrict__ q_ln_g,   const float* __restrict__ q_ln_b,
    const float* __restrict__ q_b1,     const float* __restrict__ q_b2,
    const float* __restrict__ m_ln_g,   const float* __restrict__ m_ln_b,
    const float* __restrict__ m_b1,     const float* __restrict__ m_b2,
    const float* __restrict__ m_b3,
    const short* __restrict__ wsb,
    float* __restrict__ out)
{
    __shared__ short xs[MB][LDA];
    __shared__ float sc1[MB][4];
    __shared__ float sc2[MB][4];
    __shared__ float wmask[MB], wpos[MB];
    __shared__ int   widx[MB];

    const int tid  = threadIdx.x;
    const int w    = tid >> 6;
    const int lane = tid & 63;
    const int q    = lane >> 4;
    const int ln   = lane & 15;

    const int g0 = blockIdx.x * MB;
    const int b  = g0 / Nn;
    const int n0 = g0 % Nn;

    // prefetch Q1 first k-chunk immediately (hidden under scalars+sincos+pos)
    bf16x8 bin[6];
    #pragma unroll
    for (int nt = 0; nt < 6; ++nt)
        bin[nt] = *(const bf16x8*)(wsb + Q1_OFF + ((size_t)(w * 6 + nt) * 12) * 512 + ln * 32 + q * 8);

    if (tid < MB) {
        int gi = b * Nn + n0 + tid;
        int idx = a_idx[gi];
        widx[tid]  = min(max(idx, 0), Kk - 1);
        wmask[tid] = node_mask[gi];
        wpos[tid]  = pos01[gi];
    }
    __syncthreads();

    const float* gbase = s_parent + (long)b * Kk * C;

    // ---- pos layer (transposed D): feats as B-operand, pos_w as A-operand ----
    {
        const short* pos_wb = wsb + POS_OFF;
        const bool use_sin = (q < 2);
        const int kb = (q & 1) * 8;
        bf16x8 a[4];
        #pragma unroll
        for (int mt = 0; mt < 4; ++mt) {
            float p = wpos[mt * 16 + ln];
            #pragma unroll
            for (int e = 0; e < 8; ++e) {
                float fr = (float)(1 << (kb + e)) * 3.14159265358979323846f;
                float sv, cv;
                __sincosf(p * fr, &sv, &cv);
                a[mt][e] = f2bf(use_sin ? sv : cv);
            }
        }
        f32x4 acc[4][6];
        #pragma unroll
        for (int mt = 0; mt < 4; ++mt)
            #pragma unroll
            for (int nt = 0; nt < 6; ++nt)
                acc[mt][nt] = (f32x4){0.f, 0.f, 0.f, 0.f};
        #pragma unroll
        for (int nt = 0; nt < 6; ++nt) {
            bf16x8 bfr = *(const bf16x8*)&pos_wb[(w * 6 + nt) * 512 + ln * 32 + q * 8];
            #pragma unroll
            for (int mt = 0; mt < 4; ++mt)
                acc[mt][nt] = __builtin_amdgcn_mfma_f32_16x16x32_bf16(bfr, a[mt], acc[mt][nt], 0, 0, 0);
        }
        float mk[4]; int ix[4];
        #pragma unroll
        for (int mt = 0; mt < 4; ++mt) {
            mk[mt] = wmask[mt * 16 + ln];
            ix[mt] = widx[mt * 16 + ln];
        }
        float s1[4] = {0.f,0.f,0.f,0.f}, s2[4] = {0.f,0.f,0.f,0.f};
        #pragma unroll
        for (int nt = 0; nt < 6; ++nt) {
            const int f0 = w * 96 + nt * 16 + q * 4;
            f32x4 pb4 = *(const f32x4*)&pos_b[f0];
            #pragma unroll
            for (int mt = 0; mt < 4; ++mt) {
                f32x4 g4 = *(const f32x4*)&gbase[(long)ix[mt] * C + f0];
                s16x4 o4;
                #pragma unroll
                for (int r = 0; r < 4; ++r) {
                    float v = (acc[mt][nt][r] + pb4[r]) * mk[mt] + g4[r];
                    s1[mt] += v; s2[mt] += v * v;
                    o4[r] = f2bf(v);
                }
                *(s16x4*)&xs[mt * 16 + ln][f0] = o4;
            }
        }
        #pragma unroll
        for (int mt = 0; mt < 4; ++mt) {
            s1[mt] += __shfl_xor(s1[mt], 16); s2[mt] += __shfl_xor(s2[mt], 16);
            s1[mt] += __shfl_xor(s1[mt], 32); s2[mt] += __shfl_xor(s2[mt], 32);
        }
        if (q == 0) {
            #pragma unroll
            for (int mt = 0; mt < 4; ++mt) {
                sc1[mt * 16 + ln][w] = s1[mt];
                sc2[mt * 16 + ln][w] = s2[mt];
            }
        }
    }
    __syncthreads();

    ln_apply(xs, q_ln_g, q_ln_b, sc1, sc2, tid);
    __syncthreads();

    layer_ip<384, 6, 6, 384, true,  false, false>(wsb + Q1_OFF, q_b1, w * 96,
        wsb + Q2_OFF, w * 96, bin, xs, sc1, sc2, wmask, w, q, ln);
    layer_ip<384, 6, 4, 384, false, true,  true >(wsb + Q2_OFF, q_b2, w * 96,
        wsb + M1_OFF, w * 64, bin, xs, sc1, sc2, wmask, w, q, ln);

    ln_apply(xs, m_ln_g, m_ln_b, sc1, sc2, tid);
    __syncthreads();

    layer_ip<384, 4, 4, 256, true, false, false>(wsb + M1_OFF, m_b1, w * 64,
        wsb + M2_OFF, w * 64, bin, xs, sc1, sc2, wmask, w, q, ln);
    layer_ip<256, 4, 1, 256, true, false, false>(wsb + M2_OFF, m_b2, w * 64,
        wsb + M3_OFF, 0, bin, xs, sc1, sc2, wmask, w, q, ln);

    // ---- tail: 256->3 MFMA transposed (wave w owns m-tile w), tanh*1.5 ----
    {
        const short* W3 = wsb + M3_OFF;
        f32x4 a3 = (f32x4){0.f, 0.f, 0.f, 0.f};
        #pragma unroll
        for (int kc = 0; kc < 8; ++kc) {
            bf16x8 a  = *(const bf16x8*)&xs[w * 16 + ln][kc * 32 + q * 8];
            bf16x8 bf = (kc == 0) ? bin[0]
                      : *(const bf16x8*)(W3 + kc * 512 + ln * 32 + q * 8);
            a3 = __builtin_amdgcn_mfma_f32_16x16x32_bf16(bf, a, a3, 0, 0, 0);
        }
        if (q == 0) {
            int m = w * 16 + ln;
            float mkv = wmask[m];
            #pragma unroll
            for (int r = 0; r < 3; ++r) {
                float v = (a3[r] + m_b3[r]) * mkv;
                sc1[m][r] = tanhf(v) * 1.5f;
            }
        }
    }

    // ---- rigid apply + outputs ----
    if (lane < 16) {
        int m = w * 16 + lane;
        long gi = (long)b * Nn + n0 + m;
        long pk = (long)b * Kk + widx[m];
        float mkv = wmask[m];
        float xv[3], yv[3], xiv[3];
        #pragma unroll
        for (int j = 0; j < 3; ++j) {
            xiv[j] = sc1[m][j];
            float sc = fmaxf(s_k[pk * 3 + j], 1e-8f);
            xv[j] = xiv[j] * sc;
        }
        #pragma unroll
        for (int i = 0; i < 3; ++i) {
            float a = R_k[pk * 9 + i * 3 + 0] * xv[0]
                    + R_k[pk * 9 + i * 3 + 1] * xv[1]
                    + R_k[pk * 9 + i * 3 + 2] * xv[2]
                    + mu_k[pk * 3 + i];
            yv[i] = a * mkv * 10.f;
        }
        float* o0 = out;
        float* o1 = out + (long)Bb * Nn * 3;
        float* o2 = out + (long)Bb * Nn * 6;
        #pragma unroll
        for (int j = 0; j < 3; ++j) { o0[gi * 3 + j] = xiv[j]; o1[gi * 3 + j] = yv[j]; }
        o2[gi] = wpos[m];
    }
}

extern "C" void kernel_launch(void* const* d_in, const int* in_sizes, int n_in,
                              void* d_out, int out_size, void* d_ws, size_t ws_size,
                              hipStream_t stream) {
    const float* s_parent = (const float*)d_in[0];
    const float* mu_k     = (const float*)d_in[1];
    const float* R_k      = (const float*)d_in[2];
    const float* s_k      = (const float*)d_in[3];
    const int*   a_idx    = (const int*)  d_in[4];
    const float* node_mask= (const float*)d_in[5];
    const float* pos01    = (const float*)d_in[6];
    const float* pos_w    = (const float*)d_in[7];
    const float* pos_b    = (const float*)d_in[8];
    const float* q_ln_g   = (const float*)d_in[9];
    const float* q_ln_b   = (const float*)d_in[10];
    const float* q_w1     = (const float*)d_in[11];
    const float* q_b1     = (const float*)d_in[12];
    const float* q_w2     = (const float*)d_in[13];
    const float* q_b2     = (const float*)d_in[14];
    const float* m_ln_g   = (const float*)d_in[15];
    const float* m_ln_b   = (const float*)d_in[16];
    const float* m_w1     = (const float*)d_in[17];
    const float* m_b1     = (const float*)d_in[18];
    const float* m_w2     = (const float*)d_in[19];
    const float* m_b2     = (const float*)d_in[20];
    const float* m_w3     = (const float*)d_in[21];
    const float* m_b3     = (const float*)d_in[22];

    short* wsb = (short*)d_ws;

    conv_w<<<(W_TOTAL + 255) / 256, 256, 0, stream>>>(
        pos_w, q_w1, q_w2, m_w1, m_w2, m_w3, wsb);

    int blocks = (Bb * Nn) / MB;  // 1024
    upxi64<<<blocks, 256, 0, stream>>>(
        s_parent, mu_k, R_k, s_k, a_idx, node_mask, pos01,
        pos_b, q_ln_g, q_ln_b, q_b1, q_b2,
        m_ln_g, m_ln_b, m_b1, m_b2, m_b3,
        wsb, (float*)d_out);
}

// Round 8
// 208.030 us; speedup vs baseline: 2.8954x; 1.0881x over previous
//
#include <hip/hip_runtime.h>
#include <hip/hip_bf16.h>
#include <math.h>

#define C 384
#define NF 16
#define H 256
#define Bb 4
#define Kk 2048
#define Nn 16384
#define MB 64           // nodes per block (4 m-tiles)
#define LDA 392         // act row stride in shorts

typedef __attribute__((ext_vector_type(8))) short bf16x8;
typedef __attribute__((ext_vector_type(4))) float f32x4;
typedef __attribute__((ext_vector_type(4))) short s16x4;

// ws layout (shorts), fragment-linear: [ntile][kchunk][ln(16)][kq(32)]
#define POS_OFF 0            // pos_w  F=384 K=32
#define Q1_OFF  12288        // q_w1*q_ln_g   F=384 K=384
#define Q2_OFF  159744       // q_w2          F=384 K=384
#define M1_OFF  307200       // m_w1*m_ln_g   F=256 K=384
#define M2_OFF  405504       // m_w2          F=256 K=256
#define M3_OFF  471040       // m_w3 padded [16][256]
#define W_TOTAL 475136
// float constants after the shorts (byte offset 950272, 16B aligned)
#define GQ_OFF 0
#define CQ_OFF 384
#define GM_OFF 768
#define CM_OFF 1024

__device__ __attribute__((always_inline)) inline short f2bf(float x) {
    return __builtin_bit_cast(short, __float2bfloat16(x));
}
__device__ __attribute__((always_inline)) inline float bf2f(short s) {
    return __bfloat162float(__builtin_bit_cast(__hip_bfloat16, s));
}
__device__ __attribute__((always_inline)) inline float silu(float v) {
    return v * __builtin_amdgcn_rcpf(1.f + __expf(-v));
}

// ---- weight f32->bf16 + fragment-linear swizzle; LN-g folded into Q1/M1 ----
__global__ __launch_bounds__(256) void conv_w(
    const float* __restrict__ pos_w, const float* __restrict__ q_w1,
    const float* __restrict__ q_w2,  const float* __restrict__ m_w1,
    const float* __restrict__ m_w2,  const float* __restrict__ m_w3,
    const float* __restrict__ q_ln_g, const float* __restrict__ m_ln_g,
    short* __restrict__ ws)
{
    int i = blockIdx.x * 256 + threadIdx.x;
    if (i >= W_TOTAL) return;
    const float* src; int off, K;
    if      (i < Q1_OFF) { src = pos_w; off = POS_OFF; K = 32; }
    else if (i < Q2_OFF) { src = q_w1;  off = Q1_OFF;  K = 384; }
    else if (i < M1_OFF) { src = q_w2;  off = Q2_OFF;  K = 384; }
    else if (i < M2_OFF) { src = m_w1;  off = M1_OFF;  K = 384; }
    else if (i < M3_OFF) { src = m_w2;  off = M2_OFF;  K = 256; }
    else                 { src = m_w3;  off = M3_OFF;  K = 256; }
    int t = i - off;
    int chunk = t >> 9, r = t & 511;
    int ln = r >> 5, kq = r & 31;
    int NKm = K >> 5;
    int ntg = chunk / NKm, kk = chunk - ntg * NKm;
    int f = ntg * 16 + ln, k = kk * 32 + kq;
    float v;
    if (off == M3_OFF) v = (f < 3) ? m_w3[f * 256 + k] : 0.f;
    else               v = src[(size_t)f * K + k];
    if (off == Q1_OFF) v *= q_ln_g[k];
    if (off == M1_OFF) v *= m_ln_g[k];
    ws[i] = f2bf(v);
}

// ---- fold LN constants: G[f]=sum_k bf16(W*g)[f][k]; C[f]=sum_k W[f][k]*b_ln[k]+bias[f]
__global__ __launch_bounds__(256) void fold_consts(
    const float* __restrict__ q_w1, const float* __restrict__ q_b1,
    const float* __restrict__ q_ln_g, const float* __restrict__ q_ln_b,
    const float* __restrict__ m_w1, const float* __restrict__ m_b1,
    const float* __restrict__ m_ln_g, const float* __restrict__ m_ln_b,
    float* __restrict__ cst)
{
    int f = blockIdx.x * 256 + threadIdx.x;
    if (f < 384) {
        float g = 0.f, c = 0.f;
        for (int k = 0; k < 384; ++k) {
            float w = q_w1[(size_t)f * 384 + k];
            g += bf2f(f2bf(w * q_ln_g[k]));   // match MFMA's bf16-rounded weights
            c += w * q_ln_b[k];
        }
        cst[GQ_OFF + f] = g;
        cst[CQ_OFF + f] = c + q_b1[f];
    } else if (f < 640) {
        int f2 = f - 384;
        float g = 0.f, c = 0.f;
        for (int k = 0; k < 384; ++k) {
            float w = m_w1[(size_t)f2 * 384 + k];
            g += bf2f(f2bf(w * m_ln_g[k]));
            c += w * m_ln_b[k];
        }
        cst[GM_OFF + f2] = g;
        cst[CM_OFF + f2] = c + m_b1[f2];
    }
}

// In-place FC layer, 2-deep pipelined k-loop, transposed D (weights as A-op):
// thread (q,ln) holds D[f=FB+nt*16+q*4+r][m=mt*16+ln].
// LNIN: input is raw pre-LN activations; weights are g-folded; epilogue applies
//       v = rstd*acc - (rstd*mean)*G[f] + C[f] with per-node stats from sc1/sc2.
template<int K, int NT, int NTN, int KN, bool SILU_, bool MASK, bool LNIN, bool STATS>
__device__ __attribute__((always_inline)) inline void layer_ip(
    const short* __restrict__ W, const float* __restrict__ cb,
    const float* __restrict__ Gf, int FB,
    const short* __restrict__ Wn, int FBn,
    bf16x8 (&bin)[6],
    short (*__restrict__ xs)[LDA],
    float (*__restrict__ sc1)[4], float (*__restrict__ sc2)[4],
    const float* __restrict__ wmask, int w, int q, int ln)
{
    constexpr int NK = K / 32;
    const short* bp[NT];
    #pragma unroll
    for (int nt = 0; nt < NT; ++nt)
        bp[nt] = W + ((size_t)(FB / 16 + nt) * NK) * 512 + ln * 32 + q * 8;

    f32x4 acc[4][NT];
    #pragma unroll
    for (int mt = 0; mt < 4; ++mt)
        #pragma unroll
        for (int nt = 0; nt < NT; ++nt)
            acc[mt][nt] = (f32x4){0.f, 0.f, 0.f, 0.f};

    bf16x8 b0[NT], b1[NT], a0[4], a1[4];
    #pragma unroll
    for (int nt = 0; nt < NT; ++nt) b0[nt] = bin[nt];
    #pragma unroll
    for (int mt = 0; mt < 4; ++mt) a0[mt] = *(const bf16x8*)&xs[mt * 16 + ln][q * 8];

    #pragma unroll
    for (int kc = 0; kc < NK; kc += 2) {
        #pragma unroll
        for (int nt = 0; nt < NT; ++nt) b1[nt] = *(const bf16x8*)(bp[nt] + (kc + 1) * 512);
        #pragma unroll
        for (int mt = 0; mt < 4; ++mt) a1[mt] = *(const bf16x8*)&xs[mt * 16 + ln][(kc + 1) * 32 + q * 8];
        #pragma unroll
        for (int nt = 0; nt < NT; ++nt)
            #pragma unroll
            for (int mt = 0; mt < 4; ++mt)
                acc[mt][nt] = __builtin_amdgcn_mfma_f32_16x16x32_bf16(b0[nt], a0[mt], acc[mt][nt], 0, 0, 0);
        if (kc + 2 < NK) {
            #pragma unroll
            for (int nt = 0; nt < NT; ++nt) b0[nt] = *(const bf16x8*)(bp[nt] + (kc + 2) * 512);
            #pragma unroll
            for (int mt = 0; mt < 4; ++mt) a0[mt] = *(const bf16x8*)&xs[mt * 16 + ln][(kc + 2) * 32 + q * 8];
        }
        #pragma unroll
        for (int nt = 0; nt < NT; ++nt)
            #pragma unroll
            for (int mt = 0; mt < 4; ++mt)
                acc[mt][nt] = __builtin_amdgcn_mfma_f32_16x16x32_bf16(b1[nt], a1[mt], acc[mt][nt], 0, 0, 0);
    }

    // prefetch NEXT layer's first k-chunk — rides across barrier + epilogue
    #pragma unroll
    for (int nt = 0; nt < NTN; ++nt)
        bin[nt] = *(const bf16x8*)(Wn + ((size_t)(FBn / 16 + nt) * (KN / 32)) * 512 + ln * 32 + q * 8);

    __syncthreads();   // all reads of xs complete before any in-place write

    float mk[4], rstd[4], rm[4];
    #pragma unroll
    for (int mt = 0; mt < 4; ++mt) {
        int m = mt * 16 + ln;
        if (MASK) mk[mt] = wmask[m];
        if (LNIN) {
            f32x4 p1 = *(const f32x4*)&sc1[m][0];
            f32x4 p2 = *(const f32x4*)&sc2[m][0];
            float t1 = p1[0] + p1[1] + p1[2] + p1[3];
            float t2 = p2[0] + p2[1] + p2[2] + p2[3];
            float mean = t1 * (1.f / 384.f);
            float var  = t2 * (1.f / 384.f) - mean * mean;
            rstd[mt] = rsqrtf(var + 1e-5f);
            rm[mt]   = rstd[mt] * mean;
        }
    }

    float s1[4] = {0.f,0.f,0.f,0.f}, s2[4] = {0.f,0.f,0.f,0.f};
    #pragma unroll
    for (int nt = 0; nt < NT; ++nt) {
        const int f0 = FB + nt * 16 + q * 4;
        f32x4 c4 = *(const f32x4*)&cb[f0];
        f32x4 g4;
        if (LNIN) g4 = *(const f32x4*)&Gf[f0];
        #pragma unroll
        for (int mt = 0; mt < 4; ++mt) {
            s16x4 o4;
            #pragma unroll
            for (int r = 0; r < 4; ++r) {
                float v;
                if (LNIN) v = fmaf(rstd[mt], acc[mt][nt][r], fmaf(-rm[mt], g4[r], c4[r]));
                else      v = acc[mt][nt][r] + c4[r];
                if (SILU_) v = silu(v);
                if (MASK) v *= mk[mt];
                if (STATS) { s1[mt] += v; s2[mt] += v * v; }
                o4[r] = f2bf(v);
            }
            *(s16x4*)&xs[mt * 16 + ln][f0] = o4;
        }
    }
    if (STATS) {
        #pragma unroll
        for (int mt = 0; mt < 4; ++mt) {
            s1[mt] += __shfl_xor(s1[mt], 16); s2[mt] += __shfl_xor(s2[mt], 16);
            s1[mt] += __shfl_xor(s1[mt], 32); s2[mt] += __shfl_xor(s2[mt], 32);
        }
        if (q == 0) {
            #pragma unroll
            for (int mt = 0; mt < 4; ++mt) {
                sc1[mt * 16 + ln][w] = s1[mt];
                sc2[mt * 16 + ln][w] = s2[mt];
            }
        }
    }
    __syncthreads();   // writes (xs and sc) visible before next layer
}

__global__ __launch_bounds__(256, 2) void upxi64(
    const float* __restrict__ s_parent, const float* __restrict__ mu_k,
    const float* __restrict__ R_k,      const float* __restrict__ s_k,
    const int*   __restrict__ a_idx,    const float* __restrict__ node_mask,
    const float* __restrict__ pos01,
    const float* __restrict__ pos_b,
    const float* __restrict__ q_b2,     const float* __restrict__ m_b2,
    const float* __restrict__ m_b3,
    const short* __restrict__ wsb,      const float* __restrict__ cst,
    float* __restrict__ out)
{
    __shared__ short xs[MB][LDA];
    __shared__ float sc1[MB][4];
    __shared__ float sc2[MB][4];
    __shared__ float wmask[MB], wpos[MB];
    __shared__ int   widx[MB];

    const int tid  = threadIdx.x;
    const int w    = tid >> 6;
    const int lane = tid & 63;
    const int q    = lane >> 4;
    const int ln   = lane & 15;

    const int g0 = blockIdx.x * MB;
    const int b  = g0 / Nn;
    const int n0 = g0 % Nn;

    // prefetch Q1 first k-chunk immediately (hidden under scalars+sincos+pos)
    bf16x8 bin[6];
    #pragma unroll
    for (int nt = 0; nt < 6; ++nt)
        bin[nt] = *(const bf16x8*)(wsb + Q1_OFF + ((size_t)(w * 6 + nt) * 12) * 512 + ln * 32 + q * 8);

    if (tid < MB) {
        int gi = b * Nn + n0 + tid;
        int idx = a_idx[gi];
        widx[tid]  = min(max(idx, 0), Kk - 1);
        wmask[tid] = node_mask[gi];
        wpos[tid]  = pos01[gi];
    }
    __syncthreads();

    const float* gbase = s_parent + (long)b * Kk * C;

    // ---- pos layer (transposed D): pos_w as A-operand, feats as B-operand ----
    {
        const short* pos_wb = wsb + POS_OFF;
        const bool use_sin = (q < 2);
        const int kb = (q & 1) * 8;
        bf16x8 a[4];
        #pragma unroll
        for (int mt = 0; mt < 4; ++mt) {
            float p = wpos[mt * 16 + ln];
            #pragma unroll
            for (int e = 0; e < 8; ++e) {
                float fr = (float)(1 << (kb + e)) * 3.14159265358979323846f;
                float sv, cv;
                __sincosf(p * fr, &sv, &cv);
                a[mt][e] = f2bf(use_sin ? sv : cv);
            }
        }
        f32x4 acc[4][6];
        #pragma unroll
        for (int mt = 0; mt < 4; ++mt)
            #pragma unroll
            for (int nt = 0; nt < 6; ++nt)
                acc[mt][nt] = (f32x4){0.f, 0.f, 0.f, 0.f};
        #pragma unroll
        for (int nt = 0; nt < 6; ++nt) {
            bf16x8 bfr = *(const bf16x8*)&pos_wb[(w * 6 + nt) * 512 + ln * 32 + q * 8];
            #pragma unroll
            for (int mt = 0; mt < 4; ++mt)
                acc[mt][nt] = __builtin_amdgcn_mfma_f32_16x16x32_bf16(bfr, a[mt], acc[mt][nt], 0, 0, 0);
        }
        float mk[4]; int ix[4];
        #pragma unroll
        for (int mt = 0; mt < 4; ++mt) {
            mk[mt] = wmask[mt * 16 + ln];
            ix[mt] = widx[mt * 16 + ln];
        }
        float s1[4] = {0.f,0.f,0.f,0.f}, s2[4] = {0.f,0.f,0.f,0.f};
        #pragma unroll
        for (int nt = 0; nt < 6; ++nt) {
            const int f0 = w * 96 + nt * 16 + q * 4;
            f32x4 pb4 = *(const f32x4*)&pos_b[f0];
            #pragma unroll
            for (int mt = 0; mt < 4; ++mt) {
                f32x4 g4 = *(const f32x4*)&gbase[(long)ix[mt] * C + f0];
                s16x4 o4;
                #pragma unroll
                for (int r = 0; r < 4; ++r) {
                    float v = (acc[mt][nt][r] + pb4[r]) * mk[mt] + g4[r];
                    s1[mt] += v; s2[mt] += v * v;
                    o4[r] = f2bf(v);
                }
                *(s16x4*)&xs[mt * 16 + ln][f0] = o4;
            }
        }
        #pragma unroll
        for (int mt = 0; mt < 4; ++mt) {
            s1[mt] += __shfl_xor(s1[mt], 16); s2[mt] += __shfl_xor(s2[mt], 16);
            s1[mt] += __shfl_xor(s1[mt], 32); s2[mt] += __shfl_xor(s2[mt], 32);
        }
        if (q == 0) {
            #pragma unroll
            for (int mt = 0; mt < 4; ++mt) {
                sc1[mt * 16 + ln][w] = s1[mt];
                sc2[mt * 16 + ln][w] = s2[mt];
            }
        }
    }
    __syncthreads();

    // Q1: LN(q) folded: v = silu(rstd*acc - rm*Gq + Cq)
    layer_ip<384, 6, 6, 384, true,  false, true,  false>(wsb + Q1_OFF, cst + CQ_OFF,
        cst + GQ_OFF, w * 96, wsb + Q2_OFF, w * 96, bin, xs, sc1, sc2, wmask, w, q, ln);
    // Q2: (acc + b2)*mask, stats for m-LN
    layer_ip<384, 6, 4, 384, false, true,  false, true >(wsb + Q2_OFF, q_b2,
        nullptr, w * 96, wsb + M1_OFF, w * 64, bin, xs, sc1, sc2, wmask, w, q, ln);
    // M1: LN(m) folded: v = silu(rstd*acc - rm*Gm + Cm)
    layer_ip<384, 4, 4, 256, true,  false, true,  false>(wsb + M1_OFF, cst + CM_OFF,
        cst + GM_OFF, w * 64, wsb + M2_OFF, w * 64, bin, xs, sc1, sc2, wmask, w, q, ln);
    // M2: silu(acc + b2)
    layer_ip<256, 4, 1, 256, true,  false, false, false>(wsb + M2_OFF, m_b2,
        nullptr, w * 64, wsb + M3_OFF, 0, bin, xs, sc1, sc2, wmask, w, q, ln);

    // ---- tail: 256->3 MFMA transposed (wave w owns m-tile w), tanh*1.5 ----
    {
        const short* W3 = wsb + M3_OFF;
        f32x4 a3 = (f32x4){0.f, 0.f, 0.f, 0.f};
        #pragma unroll
        for (int kc = 0; kc < 8; ++kc) {
            bf16x8 a  = *(const bf16x8*)&xs[w * 16 + ln][kc * 32 + q * 8];
            bf16x8 bf = (kc == 0) ? bin[0]
                      : *(const bf16x8*)(W3 + kc * 512 + ln * 32 + q * 8);
            a3 = __builtin_amdgcn_mfma_f32_16x16x32_bf16(bf, a, a3, 0, 0, 0);
        }
        if (q == 0) {
            int m = w * 16 + ln;
            float mkv = wmask[m];
            #pragma unroll
            for (int r = 0; r < 3; ++r) {
                float v = (a3[r] + m_b3[r]) * mkv;
                sc1[m][r] = tanhf(v) * 1.5f;
            }
        }
    }

    // ---- rigid apply + outputs (same-wave lanes, no barrier needed) ----
    if (lane < 16) {
        int m = w * 16 + lane;
        long gi = (long)b * Nn + n0 + m;
        long pk = (long)b * Kk + widx[m];
        float mkv = wmask[m];
        float xv[3], yv[3], xiv[3];
        #pragma unroll
        for (int j = 0; j < 3; ++j) {
            xiv[j] = sc1[m][j];
            float sc = fmaxf(s_k[pk * 3 + j], 1e-8f);
            xv[j] = xiv[j] * sc;
        }
        #pragma unroll
        for (int i = 0; i < 3; ++i) {
            float a = R_k[pk * 9 + i * 3 + 0] * xv[0]
                    + R_k[pk * 9 + i * 3 + 1] * xv[1]
                    + R_k[pk * 9 + i * 3 + 2] * xv[2]
                    + mu_k[pk * 3 + i];
            yv[i] = a * mkv * 10.f;
        }
        float* o0 = out;
        float* o1 = out + (long)Bb * Nn * 3;
        float* o2 = out + (long)Bb * Nn * 6;
        #pragma unroll
        for (int j = 0; j < 3; ++j) { o0[gi * 3 + j] = xiv[j]; o1[gi * 3 + j] = yv[j]; }
        o2[gi] = wpos[m];
    }
}

extern "C" void kernel_launch(void* const* d_in, const int* in_sizes, int n_in,
                              void* d_out, int out_size, void* d_ws, size_t ws_size,
                              hipStream_t stream) {
    const float* s_parent = (const float*)d_in[0];
    const float* mu_k     = (const float*)d_in[1];
    const float* R_k      = (const float*)d_in[2];
    const float* s_k      = (const float*)d_in[3];
    const int*   a_idx    = (const int*)  d_in[4];
    const float* node_mask= (const float*)d_in[5];
    const float* pos01    = (const float*)d_in[6];
    const float* pos_w    = (const float*)d_in[7];
    const float* pos_b    = (const float*)d_in[8];
    const float* q_ln_g   = (const float*)d_in[9];
    const float* q_ln_b   = (const float*)d_in[10];
    const float* q_w1     = (const float*)d_in[11];
    const float* q_b1     = (const float*)d_in[12];
    const float* q_w2     = (const float*)d_in[13];
    const float* q_b2     = (const float*)d_in[14];
    const float* m_ln_g   = (const float*)d_in[15];
    const float* m_ln_b   = (const float*)d_in[16];
    const float* m_w1     = (const float*)d_in[17];
    const float* m_b1     = (const float*)d_in[18];
    const float* m_w2     = (const float*)d_in[19];
    const float* m_b2     = (const float*)d_in[20];
    const float* m_w3     = (const float*)d_in[21];
    const float* m_b3     = (const float*)d_in[22];

    short* wsb = (short*)d_ws;
    float* cst = (float*)(wsb + W_TOTAL);

    conv_w<<<(W_TOTAL + 255) / 256, 256, 0, stream>>>(
        pos_w, q_w1, q_w2, m_w1, m_w2, m_w3, q_ln_g, m_ln_g, wsb);
    fold_consts<<<3, 256, 0, stream>>>(
        q_w1, q_b1, q_ln_g, q_ln_b, m_w1, m_b1, m_ln_g, m_ln_b, cst);

    int blocks = (Bb * Nn) / MB;  // 1024
    upxi64<<<blocks, 256, 0, stream>>>(
        s_parent, mu_k, R_k, s_k, a_idx, node_mask, pos01,
        pos_b, q_b2, m_b2, m_b3, wsb, cst, (float*)d_out);
}